// Round 1
// baseline (5288.943 us; speedup 1.0000x reference)
//
#include <hip/hip_runtime.h>

// ---------------------------------------------------------------------------
// TEN_Encoder: B=8 T=2048 D=512 C=4 K=16 L=6.  Full fp32 implementation.
// Scan is linear: z_t = z_{t-1} * M + u_t, M = diag(sigmoid(a)*e^{i w}) * R,
// u = (x @ cWinR^T) with cWinR[c,j,d] = sum_k cWin[c,k,d] * R[c,k,j].
// Chunked exact parallel scan: S=64 steps/chunk, G=32 chunks, 32 (c,b) chains.
// ---------------------------------------------------------------------------

#define BB 8
#define TT 2048
#define DD 512
#define CC 4
#define KK 16
#define LL 6
#define MM_ROWS (BB * TT)      // 16384
#define SCHUNK 64
#define NCHUNK 32              // TT / SCHUNK

typedef __attribute__((ext_vector_type(4))) float f32x4;

__device__ inline void wred2(float& a, float& b) {
#pragma unroll
  for (int off = 32; off; off >>= 1) {
    a += __shfl_xor(a, off);
    b += __shfl_xor(b, off);
  }
}

// ---------------------------------------------------------------------------
// Weight prep
// ---------------------------------------------------------------------------

// cWinR[l][(c*16+j)][d] = sum_k cWin[l,c,k,d] * R[l,c,k,j]
__global__ __launch_bounds__(256) void fold_cwin(const float* __restrict__ cWin,
                                                 const float* __restrict__ R,
                                                 float* __restrict__ cWinR) {
  int bid = blockIdx.x;            // (l*4+c)*16 + j, 384 blocks
  int j = bid & 15, lc = bid >> 4;
  int l = lc >> 2, c = lc & 3;
  for (int d = threadIdx.x; d < DD; d += 256) {
    float s = 0.f;
#pragma unroll
    for (int k = 0; k < 16; ++k)
      s += cWin[(lc * 16 + k) * DD + d] * R[(lc * 16 + k) * 16 + j];
    cWinR[((size_t)l * 64 + c * 16 + j) * DD + d] = s;
  }
}

// WoutT[l][c][k][d] = Wout[l][c][d][k]
__global__ __launch_bounds__(256) void transpose_wout(const float* __restrict__ Wout,
                                                      float* __restrict__ WoutT) {
  int bid = blockIdx.x;            // lc*16 + k, 384 blocks
  int k = bid & 15, lc = bid >> 4;
  for (int d = threadIdx.x; d < DD; d += 256)
    WoutT[(size_t)bid * DD + d] = Wout[((size_t)lc * DD + d) * 16 + k];
}

// Mall[lc*512 + plane*256 + k*16 + j]: plane0 = Re(M), plane1 = Im(M)
// M[k][j] = sigmoid(alpha[k]) * e^{i omega[k]} * R[k][j]
__global__ __launch_bounds__(256) void build_M(const float* __restrict__ alpha,
                                               const float* __restrict__ omega,
                                               const float* __restrict__ R,
                                               float* __restrict__ Mall) {
  int lc = blockIdx.x;             // 24 blocks
  int tid = threadIdx.x;           // k*16+j
  int k = tid >> 4, j = tid & 15;
  float a = alpha[lc * 16 + k];
  float mag = 1.f / (1.f + expf(-a));
  float om = omega[lc * 16 + k];
  float rr = R[(lc * 16 + k) * 16 + j];
  Mall[lc * 512 + tid] = mag * cosf(om) * rr;
  Mall[lc * 512 + 256 + tid] = mag * sinf(om) * rr;
}

// MS = M^SCHUNK via 6 complex squarings (SCHUNK = 64 = 2^6)
__global__ __launch_bounds__(256) void matpow(const float* __restrict__ M,
                                              float* __restrict__ MS) {
  __shared__ float cr[256], ci[256];
  int lc = blockIdx.x, tid = threadIdx.x;
  cr[tid] = M[lc * 512 + tid];
  ci[tid] = M[lc * 512 + 256 + tid];
  __syncthreads();
  int k = tid >> 4, j = tid & 15;
  for (int it = 0; it < 6; ++it) {
    float sr = 0.f, si = 0.f;
#pragma unroll
    for (int m = 0; m < 16; ++m) {
      float ar = cr[k * 16 + m], ai = ci[k * 16 + m];
      float br = cr[m * 16 + j], bi = ci[m * 16 + j];
      sr += ar * br - ai * bi;
      si += ar * bi + ai * br;
    }
    __syncthreads();
    cr[tid] = sr; ci[tid] = si;
    __syncthreads();
  }
  MS[lc * 512 + tid] = cr[tid];
  MS[lc * 512 + 256 + tid] = ci[tid];
}

// ---------------------------------------------------------------------------
// Generic fp32 GEMM: out = A(MxK) * W(NxK)^T (+epilogue). 64x64 tile, BK=16.
// EPI: 1 = +bias, 2 = +bias +pos_emb[row%T], 3 = scatter to scan layout u[t][cb][j]
// ---------------------------------------------------------------------------
template <int EPI>
__global__ __launch_bounds__(256) void gemm64(const float* __restrict__ A,
                                              const float* __restrict__ W,
                                              const float* __restrict__ bias,
                                              const float* __restrict__ pos,
                                              float* __restrict__ out,
                                              int M, int N, int K) {
  __shared__ float As[16][68];
  __shared__ float Ws[16][68];
  const int tid = threadIdx.x;
  const int tx = tid & 15, ty = tid >> 4;
  const int m0 = blockIdx.y * 64, n0 = blockIdx.x * 64;
  const int lr = tid >> 2, lc = (tid & 3) << 2;
  const float* Ap = A + (size_t)(m0 + lr) * K + lc;
  const float* Wp = W + (size_t)(n0 + lr) * K + lc;
  float acc[4][4] = {};
  for (int k0 = 0; k0 < K; k0 += 16) {
    f32x4 av = *(const f32x4*)(Ap + k0);
    f32x4 wv = *(const f32x4*)(Wp + k0);
    __syncthreads();
#pragma unroll
    for (int q = 0; q < 4; ++q) {
      As[lc + q][lr] = av[q];
      Ws[lc + q][lr] = wv[q];
    }
    __syncthreads();
#pragma unroll
    for (int kk = 0; kk < 16; ++kk) {
      f32x4 a4 = *(const f32x4*)&As[kk][ty * 4];
      f32x4 w4 = *(const f32x4*)&Ws[kk][tx * 4];
#pragma unroll
      for (int i = 0; i < 4; ++i)
#pragma unroll
        for (int j = 0; j < 4; ++j)
          acc[i][j] = fmaf(a4[i], w4[j], acc[i][j]);
    }
  }
#pragma unroll
  for (int i = 0; i < 4; ++i) {
    int m = m0 + ty * 4 + i;
#pragma unroll
    for (int j = 0; j < 4; ++j) {
      int n = n0 + tx * 4 + j;
      float v = acc[i][j];
      if (EPI == 1 || EPI == 2) v += bias[n];
      if (EPI == 2) v += pos[(size_t)(m & (TT - 1)) * DD + n];
      if (EPI == 3) {
        int t = m & (TT - 1), b = m >> 11, cc = n >> 4, jj = n & 15;
        out[((size_t)t * 32 + cc * 8 + b) * 16 + jj] = v;
      } else {
        out[(size_t)m * N + n] = v;
      }
    }
  }
}

// Fused gate/up GEMM: P = silu(A*Wg^T + bg) * (A*Wu^T + bu).  N=1024 fixed.
__global__ __launch_bounds__(256) void gemm_gateup(const float* __restrict__ A,
                                                   const float* __restrict__ Wg,
                                                   const float* __restrict__ bg,
                                                   const float* __restrict__ Wu,
                                                   const float* __restrict__ bu,
                                                   float* __restrict__ P, int K) {
  __shared__ float As[16][68];
  __shared__ float Gs[16][68];
  __shared__ float Us[16][68];
  const int tid = threadIdx.x;
  const int tx = tid & 15, ty = tid >> 4;
  const int m0 = blockIdx.y * 64, n0 = blockIdx.x * 64;
  const int lr = tid >> 2, lc = (tid & 3) << 2;
  const float* Ap = A + (size_t)(m0 + lr) * K + lc;
  const float* Gp = Wg + (size_t)(n0 + lr) * K + lc;
  const float* Up = Wu + (size_t)(n0 + lr) * K + lc;
  float accg[4][4] = {}, accu[4][4] = {};
  for (int k0 = 0; k0 < K; k0 += 16) {
    f32x4 av = *(const f32x4*)(Ap + k0);
    f32x4 gv = *(const f32x4*)(Gp + k0);
    f32x4 uv = *(const f32x4*)(Up + k0);
    __syncthreads();
#pragma unroll
    for (int q = 0; q < 4; ++q) {
      As[lc + q][lr] = av[q];
      Gs[lc + q][lr] = gv[q];
      Us[lc + q][lr] = uv[q];
    }
    __syncthreads();
#pragma unroll
    for (int kk = 0; kk < 16; ++kk) {
      f32x4 a4 = *(const f32x4*)&As[kk][ty * 4];
      f32x4 g4 = *(const f32x4*)&Gs[kk][tx * 4];
      f32x4 u4 = *(const f32x4*)&Us[kk][tx * 4];
#pragma unroll
      for (int i = 0; i < 4; ++i)
#pragma unroll
        for (int j = 0; j < 4; ++j) {
          accg[i][j] = fmaf(a4[i], g4[j], accg[i][j]);
          accu[i][j] = fmaf(a4[i], u4[j], accu[i][j]);
        }
    }
  }
#pragma unroll
  for (int i = 0; i < 4; ++i) {
    int m = m0 + ty * 4 + i;
#pragma unroll
    for (int j = 0; j < 4; ++j) {
      int n = n0 + tx * 4 + j;
      float g = accg[i][j] + bg[n];
      float u = accu[i][j] + bu[n];
      float sg = g / (1.f + expf(-g));
      P[(size_t)m * 1024 + n] = sg * u;
    }
  }
}

// ---------------------------------------------------------------------------
// Chunked linear scan.  unit = g*32 + cb, cb = c*8+b.  16 lanes per unit.
// u layout: u[(t*32 + cb)*16 + j]
// ---------------------------------------------------------------------------

#define SCAN_STEP(uv)                                                          \
  {                                                                            \
    float nr0 = (uv), nr1 = 0.f, ni0 = 0.f, ni1 = 0.f;                         \
    _Pragma("unroll") for (int k = 0; k < 16; k += 2) {                        \
      float rka = __shfl(zr, sb | k), ika = __shfl(zi, sb | k);                \
      float rkb = __shfl(zr, sb | (k + 1)), ikb = __shfl(zi, sb | (k + 1));    \
      nr0 = fmaf(rka, Mr[k], nr0);  nr0 = fmaf(-ika, Mi[k], nr0);              \
      ni0 = fmaf(rka, Mi[k], ni0);  ni0 = fmaf(ika, Mr[k], ni0);               \
      nr1 = fmaf(rkb, Mr[k + 1], nr1); nr1 = fmaf(-ikb, Mi[k + 1], nr1);       \
      ni1 = fmaf(rkb, Mi[k + 1], ni1); ni1 = fmaf(ikb, Mr[k + 1], ni1);        \
    }                                                                          \
    zr = nr0 + nr1; zi = ni0 + ni1;                                            \
  }

__global__ __launch_bounds__(64) void scanA(const float* __restrict__ u,
                                            const float* __restrict__ M,
                                            float* __restrict__ E) {
  int unit = blockIdx.x * 4 + (threadIdx.x >> 4);
  int j = threadIdx.x & 15;
  int sb = threadIdx.x & 48;
  int g = unit >> 5, cb = unit & 31, c = cb >> 3;
  float Mr[16], Mi[16];
  const float* Mc = M + c * 512;
#pragma unroll
  for (int k = 0; k < 16; ++k) { Mr[k] = Mc[k * 16 + j]; Mi[k] = Mc[256 + k * 16 + j]; }
  float zr = 0.f, zi = 0.f;
  const float* up = u + ((size_t)g * SCHUNK * 32 + cb) * 16 + j;
  for (int s = 0; s < SCHUNK; ++s) {
    float uv = up[(size_t)s * 512];
    SCAN_STEP(uv);
  }
  float* Ep = E + ((size_t)unit * 16 + j) * 2;
  Ep[0] = zr; Ep[1] = zi;
}

__global__ __launch_bounds__(512) void scanB(const float* __restrict__ E,
                                             const float* __restrict__ MS,
                                             float* __restrict__ CI) {
  int cb = threadIdx.x >> 4, j = threadIdx.x & 15, sb = threadIdx.x & 48;
  int c = cb >> 3;
  float Mr[16], Mi[16];
  const float* Mc = MS + c * 512;
#pragma unroll
  for (int k = 0; k < 16; ++k) { Mr[k] = Mc[k * 16 + j]; Mi[k] = Mc[256 + k * 16 + j]; }
  float zr = 0.f, zi = 0.f;
  for (int g = 0; g < NCHUNK; ++g) {
    float* cp = CI + (((size_t)g * 32 + cb) * 16 + j) * 2;
    cp[0] = zr; cp[1] = zi;  // state entering chunk g
    const float* ep = E + (((size_t)g * 32 + cb) * 16 + j) * 2;
    float er = ep[0], ei = ep[1];
    SCAN_STEP(er);
    zi += ei;  // E is complex: add imaginary part of E_g after the matvec
  }
}

__global__ __launch_bounds__(64) void scanC(const float* __restrict__ u,
                                            const float* __restrict__ M,
                                            const float* __restrict__ CI,
                                            float* __restrict__ rs) {
  int unit = blockIdx.x * 4 + (threadIdx.x >> 4);
  int j = threadIdx.x & 15;
  int sb = threadIdx.x & 48;
  int g = unit >> 5, cb = unit & 31, c = cb >> 3, b = cb & 7;
  float Mr[16], Mi[16];
  const float* Mc = M + c * 512;
#pragma unroll
  for (int k = 0; k < 16; ++k) { Mr[k] = Mc[k * 16 + j]; Mi[k] = Mc[256 + k * 16 + j]; }
  const float* cp = CI + ((size_t)unit * 16 + j) * 2;
  float zr = cp[0], zi = cp[1];
  int t0 = g * SCHUNK;
  const float* up = u + ((size_t)t0 * 32 + cb) * 16 + j;
  float* rp = rs + (((size_t)b * TT + t0) * 4 + c) * 16 + j;
  for (int s = 0; s < SCHUNK; ++s) {
    float uv = up[(size_t)s * 512];
    SCAN_STEP(uv);
    rp[(size_t)s * 64] = zr;
  }
}

// ---------------------------------------------------------------------------
// Fused: cell_out proj + per-cell LN + mean over cells + residual + LN1.
// One wave per 4 rows.  rs layout: rs[row*64 + c*16 + k], row = b*T + t.
// ---------------------------------------------------------------------------
__global__ __launch_bounds__(256) void mix_ln(const float* __restrict__ rs,
                                              const float* __restrict__ WoutT,
                                              const float* __restrict__ bo,
                                              const float* __restrict__ cg,
                                              const float* __restrict__ cbv,
                                              const float* __restrict__ h,
                                              const float* __restrict__ g1,
                                              const float* __restrict__ b1v,
                                              float* __restrict__ h1) {
  int wave = threadIdx.x >> 6, lane = threadIdx.x & 63;
  int row0 = blockIdx.x * 16 + wave * 4;
  float rsv[4];
#pragma unroll
  for (int r = 0; r < 4; ++r) rsv[r] = rs[(size_t)(row0 + r) * 64 + lane];
  float mixed[4][8];
#pragma unroll
  for (int r = 0; r < 4; ++r)
#pragma unroll
    for (int q = 0; q < 8; ++q) mixed[r][q] = 0.f;
  for (int c = 0; c < 4; ++c) {
    float v[4][8];
#pragma unroll
    for (int r = 0; r < 4; ++r)
#pragma unroll
      for (int q = 0; q < 8; ++q) v[r][q] = 0.f;
#pragma unroll
    for (int k = 0; k < 16; ++k) {
      float w[8];
#pragma unroll
      for (int q = 0; q < 8; ++q) w[q] = WoutT[(size_t)(c * 16 + k) * DD + q * 64 + lane];
#pragma unroll
      for (int r = 0; r < 4; ++r) {
        float rv = __shfl(rsv[r], c * 16 + k);
#pragma unroll
        for (int q = 0; q < 8; ++q) v[r][q] = fmaf(rv, w[q], v[r][q]);
      }
    }
    float bvv[8], gv[8], bb[8];
#pragma unroll
    for (int q = 0; q < 8; ++q) {
      bvv[q] = bo[c * DD + q * 64 + lane];
      gv[q] = cg[c * DD + q * 64 + lane];
      bb[q] = cbv[c * DD + q * 64 + lane];
    }
#pragma unroll
    for (int r = 0; r < 4; ++r) {
      float s = 0.f, s2 = 0.f;
#pragma unroll
      for (int q = 0; q < 8; ++q) {
        float xv = v[r][q] + bvv[q];
        v[r][q] = xv; s += xv; s2 += xv * xv;
      }
      wred2(s, s2);
      float mean = s * (1.f / 512.f);
      float inv = rsqrtf(s2 * (1.f / 512.f) - mean * mean + 1e-5f);
#pragma unroll
      for (int q = 0; q < 8; ++q)
        mixed[r][q] += ((v[r][q] - mean) * inv * gv[q] + bb[q]) * 0.25f;
    }
  }
  float gg[8], gb[8];
#pragma unroll
  for (int q = 0; q < 8; ++q) { gg[q] = g1[q * 64 + lane]; gb[q] = b1v[q * 64 + lane]; }
#pragma unroll
  for (int r = 0; r < 4; ++r) {
    float xv[8]; float s = 0.f, s2 = 0.f;
#pragma unroll
    for (int q = 0; q < 8; ++q) {
      float t = h[(size_t)(row0 + r) * DD + q * 64 + lane] + mixed[r][q];
      xv[q] = t; s += t; s2 += t * t;
    }
    wred2(s, s2);
    float mean = s * (1.f / 512.f);
    float inv = rsqrtf(s2 * (1.f / 512.f) - mean * mean + 1e-5f);
#pragma unroll
    for (int q = 0; q < 8; ++q)
      h1[(size_t)(row0 + r) * DD + q * 64 + lane] = (xv[q] - mean) * inv * gg[q] + gb[q];
  }
}

// out_row = LN(a_row (+ r_row)) * g + b.  One wave per row.
template <int RES>
__global__ __launch_bounds__(256) void ln_res(const float* __restrict__ a,
                                              const float* __restrict__ rr,
                                              const float* __restrict__ g,
                                              const float* __restrict__ b,
                                              float* __restrict__ o) {
  int wave = threadIdx.x >> 6, lane = threadIdx.x & 63;
  int row = blockIdx.x * 4 + wave;
  float xv[8]; float s = 0.f, s2 = 0.f;
#pragma unroll
  for (int q = 0; q < 8; ++q) {
    float t = a[(size_t)row * DD + q * 64 + lane];
    if (RES) t += rr[(size_t)row * DD + q * 64 + lane];
    xv[q] = t; s += t; s2 += t * t;
  }
  wred2(s, s2);
  float mean = s * (1.f / 512.f);
  float inv = rsqrtf(s2 * (1.f / 512.f) - mean * mean + 1e-5f);
#pragma unroll
  for (int q = 0; q < 8; ++q)
    o[(size_t)row * DD + q * 64 + lane] = (xv[q] - mean) * inv * g[q * 64 + lane] + b[q * 64 + lane];
}

// ---------------------------------------------------------------------------
// Pooling + head
// ---------------------------------------------------------------------------
__global__ __launch_bounds__(256) void pool1(const float* __restrict__ h,
                                             float* __restrict__ part) {
  int b = blockIdx.y, tc = blockIdx.x;   // grid (16,8)
  for (int d = threadIdx.x; d < DD; d += 256) {
    float s = 0.f;
    for (int t = tc * 128; t < (tc + 1) * 128; ++t)
      s += h[((size_t)b * TT + t) * DD + d];
    part[(size_t)(b * 16 + tc) * DD + d] = s;
  }
}

__global__ __launch_bounds__(512) void pool2(const float* __restrict__ part,
                                             float* __restrict__ pooled) {
  int b = blockIdx.x;
  int d = threadIdx.x;
  float s = 0.f;
#pragma unroll
  for (int tc = 0; tc < 16; ++tc) s += part[(size_t)(b * 16 + tc) * DD + d];
  pooled[(size_t)b * DD + d] = s * (1.f / 2048.f);
}

__global__ __launch_bounds__(256) void head1(const float* __restrict__ pooled,
                                             const float* __restrict__ W1,
                                             const float* __restrict__ b1,
                                             float* __restrict__ hid) {
  int b = blockIdx.x, n = threadIdx.x;
  float s = b1[n];
  for (int d = 0; d < DD; ++d) s += pooled[(size_t)b * DD + d] * W1[(size_t)n * DD + d];
  hid[(size_t)b * 256 + n] = 0.5f * s * (1.f + erff(s * 0.7071067811865475f));
}

__global__ __launch_bounds__(64) void head2(const float* __restrict__ hid,
                                            const float* __restrict__ W2,
                                            const float* __restrict__ b2,
                                            float* __restrict__ out) {
  int b = blockIdx.x, lane = threadIdx.x;
  float a0 = 0.f, a1 = 0.f;
#pragma unroll
  for (int q = 0; q < 4; ++q) {
    int n = lane + q * 64;
    float hv = hid[(size_t)b * 256 + n];
    a0 = fmaf(hv, W2[n], a0);
    a1 = fmaf(hv, W2[256 + n], a1);
  }
  wred2(a0, a1);
  if (lane == 0) {
    out[b * 2 + 0] = a0 + b2[0];
    out[b * 2 + 1] = a1 + b2[1];
  }
}

// ---------------------------------------------------------------------------
// Launch
// ---------------------------------------------------------------------------
extern "C" void kernel_launch(void* const* d_in, const int* in_sizes, int n_in,
                              void* d_out, int out_size, void* d_ws, size_t ws_size,
                              hipStream_t stream) {
  const float* x    = (const float*)d_in[0];
  const float* Win  = (const float*)d_in[1];
  const float* bin_ = (const float*)d_in[2];
  const float* pos  = (const float*)d_in[3];
  const float* alpha= (const float*)d_in[4];
  const float* omega= (const float*)d_in[5];
  const float* cWin = (const float*)d_in[6];
  const float* R    = (const float*)d_in[7];
  const float* Wout = (const float*)d_in[8];
  const float* bout = (const float*)d_in[9];
  const float* clng = (const float*)d_in[10];
  const float* clnb = (const float*)d_in[11];
  const float* ln1g = (const float*)d_in[12];
  const float* ln1b = (const float*)d_in[13];
  const float* Wg   = (const float*)d_in[14];
  const float* bg   = (const float*)d_in[15];
  const float* Wu   = (const float*)d_in[16];
  const float* bu   = (const float*)d_in[17];
  const float* Wd   = (const float*)d_in[18];
  const float* bd   = (const float*)d_in[19];
  const float* ln2g = (const float*)d_in[20];
  const float* ln2b = (const float*)d_in[21];
  const float* normg= (const float*)d_in[22];
  const float* normb= (const float*)d_in[23];
  const float* W1   = (const float*)d_in[24];
  const float* b1   = (const float*)d_in[25];
  const float* W2   = (const float*)d_in[26];
  const float* b2   = (const float*)d_in[27];
  float* out = (float*)d_out;
  char* ws = (char*)d_ws;

  // workspace layout (bytes)
  float* H    = (float*)(ws + 0);                       // 16384*512*4 = 32 MB
  float* H1   = (float*)(ws + 33554432);                // 32 MB
  float* P    = (float*)(ws + 67108864);                // 16384*1024*4 = 64 MB
  float* U    = (float*)(ws + 134217728);               // 4 MB
  float* RS   = (float*)(ws + 138412032);               // 4 MB
  float* CWR  = (float*)(ws + 142606336);               // 6*64*512*4 = 768 KB
  float* WOT  = (float*)(ws + 143392768);               // 768 KB
  float* MB   = (float*)(ws + 144179200);               // 24*512*4 = 48 KB
  float* MSB  = (float*)(ws + 144228352);               // 48 KB
  float* E    = (float*)(ws + 144277504);               // 32*32*16*2*4 = 128 KB
  float* CI   = (float*)(ws + 144408576);               // 128 KB
  float* PART = (float*)(ws + 144539648);               // 256 KB
  float* POOL = (float*)(ws + 144801792);               // 16 KB
  float* HID  = (float*)(ws + 144818176);               // 8 KB

  // weight prep (cheap, redone each call for determinism)
  hipLaunchKernelGGL(fold_cwin, dim3(384), dim3(256), 0, stream, cWin, R, CWR);
  hipLaunchKernelGGL(transpose_wout, dim3(384), dim3(256), 0, stream, Wout, WOT);
  hipLaunchKernelGGL(build_M, dim3(24), dim3(256), 0, stream, alpha, omega, R, MB);
  hipLaunchKernelGGL(matpow, dim3(24), dim3(256), 0, stream, MB, MSB);

  // input projection + pos emb
  hipLaunchKernelGGL((gemm64<2>), dim3(8, 256), dim3(256), 0, stream,
                     x, Win, bin_, pos, H, MM_ROWS, DD, DD);

  for (int l = 0; l < LL; ++l) {
    hipLaunchKernelGGL((gemm64<3>), dim3(1, 256), dim3(256), 0, stream,
                       H, CWR + (size_t)l * 64 * DD, (const float*)nullptr,
                       (const float*)nullptr, U, MM_ROWS, 64, DD);
    hipLaunchKernelGGL(scanA, dim3(256), dim3(64), 0, stream, U, MB + l * 2048, E);
    hipLaunchKernelGGL(scanB, dim3(1), dim3(512), 0, stream, E, MSB + l * 2048, CI);
    hipLaunchKernelGGL(scanC, dim3(256), dim3(64), 0, stream, U, MB + l * 2048, CI, RS);
    hipLaunchKernelGGL(mix_ln, dim3(1024), dim3(256), 0, stream,
                       RS, WOT + (size_t)l * 32768, bout + l * 2048,
                       clng + l * 2048, clnb + l * 2048, H,
                       ln1g + l * 512, ln1b + l * 512, H1);
    hipLaunchKernelGGL(gemm_gateup, dim3(16, 256), dim3(256), 0, stream,
                       H1, Wg + (size_t)l * 524288, bg + l * 1024,
                       Wu + (size_t)l * 524288, bu + l * 1024, P, DD);
    hipLaunchKernelGGL((gemm64<1>), dim3(8, 256), dim3(256), 0, stream,
                       P, Wd + (size_t)l * 524288, bd + l * 512,
                       (const float*)nullptr, H, MM_ROWS, DD, 1024);
    hipLaunchKernelGGL((ln_res<1>), dim3(4096), dim3(256), 0, stream,
                       H1, H, ln2g + l * 512, ln2b + l * 512, H);
  }

  hipLaunchKernelGGL((ln_res<0>), dim3(4096), dim3(256), 0, stream,
                     H, (const float*)nullptr, normg, normb, H);
  hipLaunchKernelGGL(pool1, dim3(16, 8), dim3(256), 0, stream, H, PART);
  hipLaunchKernelGGL(pool2, dim3(8), dim3(512), 0, stream, PART, POOL);
  hipLaunchKernelGGL(head1, dim3(8), dim3(256), 0, stream, POOL, W1, b1, HID);
  hipLaunchKernelGGL(head2, dim3(8), dim3(64), 0, stream, HID, W2, b2, out);
}

// Round 2
// 2400.922 us; speedup vs baseline: 2.2029x; 2.2029x over previous
//
#include <hip/hip_runtime.h>

// ---------------------------------------------------------------------------
// TEN_Encoder: B=8 T=2048 D=512 C=4 K=16 L=6.
// Big GEMMs (input proj, gate/up, down) in f16 MFMA (fp32 accumulate).
// Scan path + mix_ln + LNs in fp32.
// ---------------------------------------------------------------------------

#define BB 8
#define TT 2048
#define DD 512
#define LL 6
#define MM_ROWS 16384
#define SCHUNK 64
#define NCHUNK 32

typedef __attribute__((ext_vector_type(4))) float f32x4;
typedef __attribute__((ext_vector_type(8))) _Float16 f16x8;
typedef __attribute__((ext_vector_type(4))) _Float16 f16x4;

#define GLOAD16(g, l)                                                          \
  __builtin_amdgcn_global_load_lds(                                            \
      (const __attribute__((address_space(1))) void*)(g),                      \
      (__attribute__((address_space(3))) void*)(l), 16, 0, 0)

__device__ inline void wred2(float& a, float& b) {
#pragma unroll
  for (int off = 32; off; off >>= 1) {
    a += __shfl_xor(a, off);
    b += __shfl_xor(b, off);
  }
}

// ---------------------------------------------------------------------------
// fp32 -> f16 convert (RNE), 4 elems/thread
// ---------------------------------------------------------------------------
__global__ __launch_bounds__(256) void to_half(const float* __restrict__ s,
                                               _Float16* __restrict__ d, int n4) {
  int i = blockIdx.x * 256 + threadIdx.x;
  if (i < n4) {
    f32x4 v = *((const f32x4*)s + i);
    f16x4 o;
#pragma unroll
    for (int q = 0; q < 4; ++q) o[q] = (_Float16)v[q];
    *((f16x4*)d + i) = o;
  }
}

// ---------------------------------------------------------------------------
// Weight prep (fp32)
// ---------------------------------------------------------------------------
__global__ __launch_bounds__(256) void fold_cwin(const float* __restrict__ cWin,
                                                 const float* __restrict__ R,
                                                 float* __restrict__ cWinR) {
  int bid = blockIdx.x;            // (l*4+c)*16 + j, 384 blocks
  int j = bid & 15, lc = bid >> 4;
  int l = lc >> 2, c = lc & 3;
  for (int d = threadIdx.x; d < DD; d += 256) {
    float s = 0.f;
#pragma unroll
    for (int k = 0; k < 16; ++k)
      s += cWin[(lc * 16 + k) * DD + d] * R[(lc * 16 + k) * 16 + j];
    cWinR[((size_t)l * 64 + c * 16 + j) * DD + d] = s;
  }
}

__global__ __launch_bounds__(256) void transpose_wout(const float* __restrict__ Wout,
                                                      float* __restrict__ WoutT) {
  int bid = blockIdx.x;            // lc*16 + k, 384 blocks
  int k = bid & 15, lc = bid >> 4;
  for (int d = threadIdx.x; d < DD; d += 256)
    WoutT[(size_t)bid * DD + d] = Wout[((size_t)lc * DD + d) * 16 + k];
}

__global__ __launch_bounds__(256) void build_M(const float* __restrict__ alpha,
                                               const float* __restrict__ omega,
                                               const float* __restrict__ R,
                                               float* __restrict__ Mall) {
  int lc = blockIdx.x;             // 24 blocks
  int tid = threadIdx.x;           // k*16+j
  int k = tid >> 4;
  float a = alpha[lc * 16 + k];
  float mag = 1.f / (1.f + expf(-a));
  float om = omega[lc * 16 + k];
  float rr = R[(lc * 16 + k) * 16 + (tid & 15)];
  Mall[lc * 512 + tid] = mag * cosf(om) * rr;
  Mall[lc * 512 + 256 + tid] = mag * sinf(om) * rr;
}

__global__ __launch_bounds__(256) void matpow(const float* __restrict__ M,
                                              float* __restrict__ MS) {
  __shared__ float cr[256], ci[256];
  int lc = blockIdx.x, tid = threadIdx.x;
  cr[tid] = M[lc * 512 + tid];
  ci[tid] = M[lc * 512 + 256 + tid];
  __syncthreads();
  int k = tid >> 4, j = tid & 15;
  for (int it = 0; it < 6; ++it) {
    float sr = 0.f, si = 0.f;
#pragma unroll
    for (int m = 0; m < 16; ++m) {
      float ar = cr[k * 16 + m], ai = ci[k * 16 + m];
      float br = cr[m * 16 + j], bi = ci[m * 16 + j];
      sr += ar * br - ai * bi;
      si += ar * bi + ai * br;
    }
    __syncthreads();
    cr[tid] = sr; ci[tid] = si;
    __syncthreads();
  }
  MS[lc * 512 + tid] = cr[tid];
  MS[lc * 512 + 256 + tid] = ci[tid];
}

// ---------------------------------------------------------------------------
// f16 MFMA GEMM: out(fp32) = A(MxK,f16) * W(NxK,f16)^T + epilogue.
// 128x128 tile, BK=32, 4 waves x (64x64), global_load_lds(16B) staging.
// LDS layout [kchunk=4][row=128][8 f16] -> conflict-free b128 frag reads.
// EPI: 1 = +bias ; 2 = +bias +pos[row%T]
// ---------------------------------------------------------------------------
template <int EPI>
__global__ __launch_bounds__(256) void mgemm(const _Float16* __restrict__ A,
                                             const _Float16* __restrict__ W,
                                             const float* __restrict__ bias,
                                             const float* __restrict__ pos,
                                             float* __restrict__ out,
                                             int M, int N, int K) {
  __shared__ alignas(16) _Float16 As[4][128][8];
  __shared__ alignas(16) _Float16 Bs[4][128][8];
  const int tid = threadIdx.x;
  const int wv = tid >> 6, lane = tid & 63;
  const int m0 = blockIdx.y << 7, n0 = blockIdx.x << 7;
  const int wr = (wv >> 1) << 6, wc = (wv & 1) << 6;
  const int r16 = lane & 15, half = lane >> 4;
  f32x4 acc[4][4] = {};
  for (int k0 = 0; k0 < K; k0 += 32) {
    __syncthreads();
#pragma unroll
    for (int q = 0; q < 2; ++q) {
      int o = (q << 8) + tid;
      int ch = o >> 7, row = o & 127;
      GLOAD16(A + (size_t)(m0 + row) * K + k0 + (ch << 3),
              (char*)As + (((q << 8) + (wv << 6)) << 4));
      GLOAD16(W + (size_t)(n0 + row) * K + k0 + (ch << 3),
              (char*)Bs + (((q << 8) + (wv << 6)) << 4));
    }
    __syncthreads();
    f16x8 af[4], bfv[4];
#pragma unroll
    for (int i = 0; i < 4; ++i)
      af[i] = *(const f16x8*)&As[half][wr + (i << 4) + r16][0];
#pragma unroll
    for (int j = 0; j < 4; ++j)
      bfv[j] = *(const f16x8*)&Bs[half][wc + (j << 4) + r16][0];
#pragma unroll
    for (int i = 0; i < 4; ++i)
#pragma unroll
      for (int j = 0; j < 4; ++j)
        acc[i][j] = __builtin_amdgcn_mfma_f32_16x16x32_f16(af[i], bfv[j], acc[i][j], 0, 0, 0);
  }
#pragma unroll
  for (int i = 0; i < 4; ++i)
#pragma unroll
    for (int j = 0; j < 4; ++j) {
      int n = n0 + wc + (j << 4) + r16;
      float bv = bias ? bias[n] : 0.f;
#pragma unroll
      for (int r = 0; r < 4; ++r) {
        int m = m0 + wr + (i << 4) + (half << 2) + r;
        float v = acc[i][j][r] + bv;
        if (EPI == 2) v += pos[(size_t)(m & (TT - 1)) * DD + n];
        out[(size_t)m * N + n] = v;
      }
    }
}

// Fused gate/up f16 MFMA GEMM: P(f16) = silu(A*Wg^T+bg) * (A*Wu^T+bu).
// M=16384, N=1024, K=512 fixed.
__global__ __launch_bounds__(256) void mgemm_gateup(const _Float16* __restrict__ A,
                                                    const _Float16* __restrict__ Wg,
                                                    const _Float16* __restrict__ Wu,
                                                    const float* __restrict__ bg,
                                                    const float* __restrict__ bu,
                                                    _Float16* __restrict__ P) {
  __shared__ alignas(16) _Float16 As[4][128][8];
  __shared__ alignas(16) _Float16 Gs[4][128][8];
  __shared__ alignas(16) _Float16 Us[4][128][8];
  const int tid = threadIdx.x;
  const int wv = tid >> 6, lane = tid & 63;
  const int m0 = blockIdx.y << 7, n0 = blockIdx.x << 7;
  const int wr = (wv >> 1) << 6, wc = (wv & 1) << 6;
  const int r16 = lane & 15, half = lane >> 4;
  f32x4 accg[4][4] = {}, accu[4][4] = {};
  for (int k0 = 0; k0 < 512; k0 += 32) {
    __syncthreads();
#pragma unroll
    for (int q = 0; q < 2; ++q) {
      int o = (q << 8) + tid;
      int ch = o >> 7, row = o & 127;
      size_t koff = (size_t)k0 + (ch << 3);
      GLOAD16(A + (size_t)(m0 + row) * 512 + koff,
              (char*)As + (((q << 8) + (wv << 6)) << 4));
      GLOAD16(Wg + (size_t)(n0 + row) * 512 + koff,
              (char*)Gs + (((q << 8) + (wv << 6)) << 4));
      GLOAD16(Wu + (size_t)(n0 + row) * 512 + koff,
              (char*)Us + (((q << 8) + (wv << 6)) << 4));
    }
    __syncthreads();
    f16x8 af[4], gf[4], uf[4];
#pragma unroll
    for (int i = 0; i < 4; ++i)
      af[i] = *(const f16x8*)&As[half][wr + (i << 4) + r16][0];
#pragma unroll
    for (int j = 0; j < 4; ++j) {
      gf[j] = *(const f16x8*)&Gs[half][wc + (j << 4) + r16][0];
      uf[j] = *(const f16x8*)&Us[half][wc + (j << 4) + r16][0];
    }
#pragma unroll
    for (int i = 0; i < 4; ++i)
#pragma unroll
      for (int j = 0; j < 4; ++j) {
        accg[i][j] = __builtin_amdgcn_mfma_f32_16x16x32_f16(af[i], gf[j], accg[i][j], 0, 0, 0);
        accu[i][j] = __builtin_amdgcn_mfma_f32_16x16x32_f16(af[i], uf[j], accu[i][j], 0, 0, 0);
      }
  }
#pragma unroll
  for (int i = 0; i < 4; ++i)
#pragma unroll
    for (int j = 0; j < 4; ++j) {
      int n = n0 + wc + (j << 4) + r16;
      float bgv = bg[n], buv = bu[n];
#pragma unroll
      for (int r = 0; r < 4; ++r) {
        int m = m0 + wr + (i << 4) + (half << 2) + r;
        float g = accg[i][j][r] + bgv;
        float u = accu[i][j][r] + buv;
        float sg = g / (1.f + expf(-g));
        P[(size_t)m * 1024 + n] = (_Float16)(sg * u);
      }
    }
}

// ---------------------------------------------------------------------------
// fp32 GEMM (kept for cWin proj, N=64): out = A*W^T, scatter to scan layout
// ---------------------------------------------------------------------------
__global__ __launch_bounds__(256) void gemm_cwin(const float* __restrict__ A,
                                                 const float* __restrict__ W,
                                                 float* __restrict__ out,
                                                 int K) {
  __shared__ float As[16][68];
  __shared__ float Ws[16][68];
  const int tid = threadIdx.x;
  const int tx = tid & 15, ty = tid >> 4;
  const int m0 = blockIdx.y * 64, n0 = blockIdx.x * 64;
  const int lr = tid >> 2, lc = (tid & 3) << 2;
  const float* Ap = A + (size_t)(m0 + lr) * K + lc;
  const float* Wp = W + (size_t)(n0 + lr) * K + lc;
  float acc[4][4] = {};
  for (int k0 = 0; k0 < K; k0 += 16) {
    f32x4 av = *(const f32x4*)(Ap + k0);
    f32x4 wv = *(const f32x4*)(Wp + k0);
    __syncthreads();
#pragma unroll
    for (int q = 0; q < 4; ++q) {
      As[lc + q][lr] = av[q];
      Ws[lc + q][lr] = wv[q];
    }
    __syncthreads();
#pragma unroll
    for (int kk = 0; kk < 16; ++kk) {
      f32x4 a4 = *(const f32x4*)&As[kk][ty * 4];
      f32x4 w4 = *(const f32x4*)&Ws[kk][tx * 4];
#pragma unroll
      for (int i = 0; i < 4; ++i)
#pragma unroll
        for (int j = 0; j < 4; ++j)
          acc[i][j] = fmaf(a4[i], w4[j], acc[i][j]);
    }
  }
#pragma unroll
  for (int i = 0; i < 4; ++i) {
    int m = m0 + ty * 4 + i;
#pragma unroll
    for (int j = 0; j < 4; ++j) {
      int n = n0 + tx * 4 + j;
      int t = m & (TT - 1), b = m >> 11, cc = n >> 4, jj = n & 15;
      out[((size_t)t * 32 + cc * 8 + b) * 16 + jj] = acc[i][j];
    }
  }
}

// ---------------------------------------------------------------------------
// Chunked linear scan (fp32), unchanged from R1
// ---------------------------------------------------------------------------
#define SCAN_STEP(uv)                                                          \
  {                                                                            \
    float nr0 = (uv), nr1 = 0.f, ni0 = 0.f, ni1 = 0.f;                         \
    _Pragma("unroll") for (int k = 0; k < 16; k += 2) {                        \
      float rka = __shfl(zr, sb | k), ika = __shfl(zi, sb | k);                \
      float rkb = __shfl(zr, sb | (k + 1)), ikb = __shfl(zi, sb | (k + 1));    \
      nr0 = fmaf(rka, Mr[k], nr0);  nr0 = fmaf(-ika, Mi[k], nr0);              \
      ni0 = fmaf(rka, Mi[k], ni0);  ni0 = fmaf(ika, Mr[k], ni0);               \
      nr1 = fmaf(rkb, Mr[k + 1], nr1); nr1 = fmaf(-ikb, Mi[k + 1], nr1);       \
      ni1 = fmaf(rkb, Mi[k + 1], ni1); ni1 = fmaf(ikb, Mr[k + 1], ni1);        \
    }                                                                          \
    zr = nr0 + nr1; zi = ni0 + ni1;                                            \
  }

__global__ __launch_bounds__(64) void scanA(const float* __restrict__ u,
                                            const float* __restrict__ M,
                                            float* __restrict__ E) {
  int unit = blockIdx.x * 4 + (threadIdx.x >> 4);
  int j = threadIdx.x & 15;
  int sb = threadIdx.x & 48;
  int g = unit >> 5, cb = unit & 31, c = cb >> 3;
  float Mr[16], Mi[16];
  const float* Mc = M + c * 512;
#pragma unroll
  for (int k = 0; k < 16; ++k) { Mr[k] = Mc[k * 16 + j]; Mi[k] = Mc[256 + k * 16 + j]; }
  float zr = 0.f, zi = 0.f;
  const float* up = u + ((size_t)g * SCHUNK * 32 + cb) * 16 + j;
  for (int s = 0; s < SCHUNK; ++s) {
    float uv = up[(size_t)s * 512];
    SCAN_STEP(uv);
  }
  float* Ep = E + ((size_t)unit * 16 + j) * 2;
  Ep[0] = zr; Ep[1] = zi;
}

__global__ __launch_bounds__(512) void scanB(const float* __restrict__ E,
                                             const float* __restrict__ MS,
                                             float* __restrict__ CI) {
  int cb = threadIdx.x >> 4, j = threadIdx.x & 15, sb = threadIdx.x & 48;
  int c = cb >> 3;
  float Mr[16], Mi[16];
  const float* Mc = MS + c * 512;
#pragma unroll
  for (int k = 0; k < 16; ++k) { Mr[k] = Mc[k * 16 + j]; Mi[k] = Mc[256 + k * 16 + j]; }
  float zr = 0.f, zi = 0.f;
  for (int g = 0; g < NCHUNK; ++g) {
    float* cp = CI + (((size_t)g * 32 + cb) * 16 + j) * 2;
    cp[0] = zr; cp[1] = zi;
    const float* ep = E + (((size_t)g * 32 + cb) * 16 + j) * 2;
    float er = ep[0], ei = ep[1];
    SCAN_STEP(er);
    zi += ei;
  }
}

__global__ __launch_bounds__(64) void scanC(const float* __restrict__ u,
                                            const float* __restrict__ M,
                                            const float* __restrict__ CI,
                                            float* __restrict__ rs) {
  int unit = blockIdx.x * 4 + (threadIdx.x >> 4);
  int j = threadIdx.x & 15;
  int sb = threadIdx.x & 48;
  int g = unit >> 5, cb = unit & 31, c = cb >> 3, b = cb & 7;
  float Mr[16], Mi[16];
  const float* Mc = M + c * 512;
#pragma unroll
  for (int k = 0; k < 16; ++k) { Mr[k] = Mc[k * 16 + j]; Mi[k] = Mc[256 + k * 16 + j]; }
  const float* cp = CI + ((size_t)unit * 16 + j) * 2;
  float zr = cp[0], zi = cp[1];
  int t0 = g * SCHUNK;
  const float* up = u + ((size_t)t0 * 32 + cb) * 16 + j;
  float* rp = rs + (((size_t)b * TT + t0) * 4 + c) * 16 + j;
  for (int s = 0; s < SCHUNK; ++s) {
    float uv = up[(size_t)s * 512];
    SCAN_STEP(uv);
    rp[(size_t)s * 64] = zr;
  }
}

// ---------------------------------------------------------------------------
// Fused: cell_out proj + per-cell LN + mean + residual + LN1.  Writes fp32 h1
// and f16 h1b (GEMM operand for gate/up).
// ---------------------------------------------------------------------------
__global__ __launch_bounds__(256) void mix_ln(const float* __restrict__ rs,
                                              const float* __restrict__ WoutT,
                                              const float* __restrict__ bo,
                                              const float* __restrict__ cg,
                                              const float* __restrict__ cbv,
                                              const float* __restrict__ h,
                                              const float* __restrict__ g1,
                                              const float* __restrict__ b1v,
                                              float* __restrict__ h1,
                                              _Float16* __restrict__ h1b) {
  int wave = threadIdx.x >> 6, lane = threadIdx.x & 63;
  int row0 = blockIdx.x * 16 + wave * 4;
  float rsv[4];
#pragma unroll
  for (int r = 0; r < 4; ++r) rsv[r] = rs[(size_t)(row0 + r) * 64 + lane];
  float mixed[4][8];
#pragma unroll
  for (int r = 0; r < 4; ++r)
#pragma unroll
    for (int q = 0; q < 8; ++q) mixed[r][q] = 0.f;
  for (int c = 0; c < 4; ++c) {
    float v[4][8];
#pragma unroll
    for (int r = 0; r < 4; ++r)
#pragma unroll
      for (int q = 0; q < 8; ++q) v[r][q] = 0.f;
#pragma unroll
    for (int k = 0; k < 16; ++k) {
      float w[8];
#pragma unroll
      for (int q = 0; q < 8; ++q) w[q] = WoutT[(size_t)(c * 16 + k) * DD + q * 64 + lane];
#pragma unroll
      for (int r = 0; r < 4; ++r) {
        float rv = __shfl(rsv[r], c * 16 + k);
#pragma unroll
        for (int q = 0; q < 8; ++q) v[r][q] = fmaf(rv, w[q], v[r][q]);
      }
    }
    float bvv[8], gv[8], bb[8];
#pragma unroll
    for (int q = 0; q < 8; ++q) {
      bvv[q] = bo[c * DD + q * 64 + lane];
      gv[q] = cg[c * DD + q * 64 + lane];
      bb[q] = cbv[c * DD + q * 64 + lane];
    }
#pragma unroll
    for (int r = 0; r < 4; ++r) {
      float s = 0.f, s2 = 0.f;
#pragma unroll
      for (int q = 0; q < 8; ++q) {
        float xv = v[r][q] + bvv[q];
        v[r][q] = xv; s += xv; s2 += xv * xv;
      }
      wred2(s, s2);
      float mean = s * (1.f / 512.f);
      float inv = rsqrtf(s2 * (1.f / 512.f) - mean * mean + 1e-5f);
#pragma unroll
      for (int q = 0; q < 8; ++q)
        mixed[r][q] += ((v[r][q] - mean) * inv * gv[q] + bb[q]) * 0.25f;
    }
  }
  float gg[8], gb[8];
#pragma unroll
  for (int q = 0; q < 8; ++q) { gg[q] = g1[q * 64 + lane]; gb[q] = b1v[q * 64 + lane]; }
#pragma unroll
  for (int r = 0; r < 4; ++r) {
    float xv[8]; float s = 0.f, s2 = 0.f;
#pragma unroll
    for (int q = 0; q < 8; ++q) {
      float t = h[(size_t)(row0 + r) * DD + q * 64 + lane] + mixed[r][q];
      xv[q] = t; s += t; s2 += t * t;
    }
    wred2(s, s2);
    float mean = s * (1.f / 512.f);
    float inv = rsqrtf(s2 * (1.f / 512.f) - mean * mean + 1e-5f);
#pragma unroll
    for (int q = 0; q < 8; ++q) {
      float val = (xv[q] - mean) * inv * gg[q] + gb[q];
      h1[(size_t)(row0 + r) * DD + q * 64 + lane] = val;
      h1b[(size_t)(row0 + r) * DD + q * 64 + lane] = (_Float16)val;
    }
  }
}

// out_row = LN(a_row (+ r_row)) * g + b.  One wave per row.
template <int RES>
__global__ __launch_bounds__(256) void ln_res(const float* __restrict__ a,
                                              const float* __restrict__ rr,
                                              const float* __restrict__ g,
                                              const float* __restrict__ b,
                                              float* __restrict__ o) {
  int wave = threadIdx.x >> 6, lane = threadIdx.x & 63;
  int row = blockIdx.x * 4 + wave;
  float xv[8]; float s = 0.f, s2 = 0.f;
#pragma unroll
  for (int q = 0; q < 8; ++q) {
    float t = a[(size_t)row * DD + q * 64 + lane];
    if (RES) t += rr[(size_t)row * DD + q * 64 + lane];
    xv[q] = t; s += t; s2 += t * t;
  }
  wred2(s, s2);
  float mean = s * (1.f / 512.f);
  float inv = rsqrtf(s2 * (1.f / 512.f) - mean * mean + 1e-5f);
#pragma unroll
  for (int q = 0; q < 8; ++q)
    o[(size_t)row * DD + q * 64 + lane] = (xv[q] - mean) * inv * g[q * 64 + lane] + b[q * 64 + lane];
}

// ---------------------------------------------------------------------------
// Pooling + head
// ---------------------------------------------------------------------------
__global__ __launch_bounds__(256) void pool1(const float* __restrict__ h,
                                             float* __restrict__ part) {
  int b = blockIdx.y, tc = blockIdx.x;   // grid (16,8)
  for (int d = threadIdx.x; d < DD; d += 256) {
    float s = 0.f;
    for (int t = tc * 128; t < (tc + 1) * 128; ++t)
      s += h[((size_t)b * TT + t) * DD + d];
    part[(size_t)(b * 16 + tc) * DD + d] = s;
  }
}

__global__ __launch_bounds__(512) void pool2(const float* __restrict__ part,
                                             float* __restrict__ pooled) {
  int b = blockIdx.x;
  int d = threadIdx.x;
  float s = 0.f;
#pragma unroll
  for (int tc = 0; tc < 16; ++tc) s += part[(size_t)(b * 16 + tc) * DD + d];
  pooled[(size_t)b * DD + d] = s * (1.f / 2048.f);
}

__global__ __launch_bounds__(256) void head1(const float* __restrict__ pooled,
                                             const float* __restrict__ W1,
                                             const float* __restrict__ b1,
                                             float* __restrict__ hid) {
  int b = blockIdx.x, n = threadIdx.x;
  float s = b1[n];
  for (int d = 0; d < DD; ++d) s += pooled[(size_t)b * DD + d] * W1[(size_t)n * DD + d];
  hid[(size_t)b * 256 + n] = 0.5f * s * (1.f + erff(s * 0.7071067811865475f));
}

__global__ __launch_bounds__(64) void head2(const float* __restrict__ hid,
                                            const float* __restrict__ W2,
                                            const float* __restrict__ b2,
                                            float* __restrict__ out) {
  int b = blockIdx.x, lane = threadIdx.x;
  float a0 = 0.f, a1 = 0.f;
#pragma unroll
  for (int q = 0; q < 4; ++q) {
    int n = lane + q * 64;
    float hv = hid[(size_t)b * 256 + n];
    a0 = fmaf(hv, W2[n], a0);
    a1 = fmaf(hv, W2[256 + n], a1);
  }
  wred2(a0, a1);
  if (lane == 0) {
    out[b * 2 + 0] = a0 + b2[0];
    out[b * 2 + 1] = a1 + b2[1];
  }
}

// ---------------------------------------------------------------------------
// Launch
// ---------------------------------------------------------------------------
extern "C" void kernel_launch(void* const* d_in, const int* in_sizes, int n_in,
                              void* d_out, int out_size, void* d_ws, size_t ws_size,
                              hipStream_t stream) {
  const float* x    = (const float*)d_in[0];
  const float* Win  = (const float*)d_in[1];
  const float* bin_ = (const float*)d_in[2];
  const float* pos  = (const float*)d_in[3];
  const float* alpha= (const float*)d_in[4];
  const float* omega= (const float*)d_in[5];
  const float* cWin = (const float*)d_in[6];
  const float* R    = (const float*)d_in[7];
  const float* Wout = (const float*)d_in[8];
  const float* bout = (const float*)d_in[9];
  const float* clng = (const float*)d_in[10];
  const float* clnb = (const float*)d_in[11];
  const float* ln1g = (const float*)d_in[12];
  const float* ln1b = (const float*)d_in[13];
  const float* Wg   = (const float*)d_in[14];
  const float* bg   = (const float*)d_in[15];
  const float* Wu   = (const float*)d_in[16];
  const float* bu   = (const float*)d_in[17];
  const float* Wd   = (const float*)d_in[18];
  const float* bd   = (const float*)d_in[19];
  const float* ln2g = (const float*)d_in[20];
  const float* ln2b = (const float*)d_in[21];
  const float* normg= (const float*)d_in[22];
  const float* normb= (const float*)d_in[23];
  const float* W1   = (const float*)d_in[24];
  const float* b1   = (const float*)d_in[25];
  const float* W2   = (const float*)d_in[26];
  const float* b2   = (const float*)d_in[27];
  float* out = (float*)d_out;
  char* ws = (char*)d_ws;

  // workspace layout (bytes)
  float*     H    = (float*)(ws + 0);              // 32 MB fp32
  float*     H1   = (float*)(ws + 33554432);       // 32 MB fp32
  _Float16*  Pb   = (_Float16*)(ws + 67108864);    // 32 MB f16 (16384x1024)
  _Float16*  xb   = (_Float16*)(ws + 67108864);    // alias: dead before Pb used
  float*     U    = (float*)(ws + 67108864);       // alias: dead before gateup
  float*     RS   = (float*)(ws + 71303168);       // alias inside Pb region
  _Float16*  H1b  = (_Float16*)(ws + 100663296);   // 16 MB f16
  float*     CWR  = (float*)(ws + 117440512);      // 768 KB
  float*     WOT  = (float*)(ws + 118226944);      // 768 KB
  _Float16*  Winb = (_Float16*)(ws + 119013376);   // 512 KB
  _Float16*  Wgb  = (_Float16*)(ws + 119537664);   // 6 MB
  _Float16*  Wub  = (_Float16*)(ws + 125829120);   // 6 MB
  _Float16*  Wdb  = (_Float16*)(ws + 132120576);   // 6 MB
  float*     MB   = (float*)(ws + 138412032);      // 48 KB
  float*     MSB  = (float*)(ws + 138461184);      // 48 KB
  float*     E    = (float*)(ws + 138510336);      // 128 KB
  float*     CI   = (float*)(ws + 138641408);      // 128 KB
  float*     PART = (float*)(ws + 138772480);      // 256 KB
  float*     POOL = (float*)(ws + 139034624);      // 16 KB
  float*     HID  = (float*)(ws + 139050496);      // 8 KB

  // f16 weight/input conversion
  hipLaunchKernelGGL(to_half, dim3(8192), dim3(256), 0, stream, x, xb, 2097152);
  hipLaunchKernelGGL(to_half, dim3(256),  dim3(256), 0, stream, Win, Winb, 65536);
  hipLaunchKernelGGL(to_half, dim3(3072), dim3(256), 0, stream, Wg, Wgb, 786432);
  hipLaunchKernelGGL(to_half, dim3(3072), dim3(256), 0, stream, Wu, Wub, 786432);
  hipLaunchKernelGGL(to_half, dim3(3072), dim3(256), 0, stream, Wd, Wdb, 786432);

  // scan weight prep
  hipLaunchKernelGGL(fold_cwin, dim3(384), dim3(256), 0, stream, cWin, R, CWR);
  hipLaunchKernelGGL(transpose_wout, dim3(384), dim3(256), 0, stream, Wout, WOT);
  hipLaunchKernelGGL(build_M, dim3(24), dim3(256), 0, stream, alpha, omega, R, MB);
  hipLaunchKernelGGL(matpow, dim3(24), dim3(256), 0, stream, MB, MSB);

  // input projection + pos emb (f16 MFMA)
  hipLaunchKernelGGL((mgemm<2>), dim3(4, 128), dim3(256), 0, stream,
                     xb, Winb, bin_, pos, H, MM_ROWS, DD, DD);

  for (int l = 0; l < LL; ++l) {
    hipLaunchKernelGGL(gemm_cwin, dim3(1, 256), dim3(256), 0, stream,
                       H, CWR + (size_t)l * 64 * DD, U, DD);
    hipLaunchKernelGGL(scanA, dim3(256), dim3(64), 0, stream, U, MB + l * 2048, E);
    hipLaunchKernelGGL(scanB, dim3(1), dim3(512), 0, stream, E, MSB + l * 2048, CI);
    hipLaunchKernelGGL(scanC, dim3(256), dim3(64), 0, stream, U, MB + l * 2048, CI, RS);
    hipLaunchKernelGGL(mix_ln, dim3(1024), dim3(256), 0, stream,
                       RS, WOT + (size_t)l * 32768, bout + l * 2048,
                       clng + l * 2048, clnb + l * 2048, H,
                       ln1g + l * 512, ln1b + l * 512, H1, H1b);
    hipLaunchKernelGGL(mgemm_gateup, dim3(8, 128), dim3(256), 0, stream,
                       H1b, Wgb + (size_t)l * 524288, Wub + (size_t)l * 524288,
                       bg + l * 1024, bu + l * 1024, Pb);
    hipLaunchKernelGGL((mgemm<1>), dim3(4, 128), dim3(256), 0, stream,
                       Pb, Wdb + (size_t)l * 524288, bd + l * 512,
                       (const float*)nullptr, H, MM_ROWS, DD, 1024);
    hipLaunchKernelGGL((ln_res<1>), dim3(4096), dim3(256), 0, stream,
                       H1, H, ln2g + l * 512, ln2b + l * 512, H);
  }

  hipLaunchKernelGGL((ln_res<0>), dim3(4096), dim3(256), 0, stream,
                     H, (const float*)nullptr, normg, normb, H);
  hipLaunchKernelGGL(pool1, dim3(16, 8), dim3(256), 0, stream, H, PART);
  hipLaunchKernelGGL(pool2, dim3(8), dim3(512), 0, stream, PART, POOL);
  hipLaunchKernelGGL(head1, dim3(8), dim3(256), 0, stream, POOL, W1, b1, HID);
  hipLaunchKernelGGL(head2, dim3(8), dim3(64), 0, stream, HID, W2, b2, out);
}

// Round 3
// 2152.090 us; speedup vs baseline: 2.4576x; 1.1156x over previous
//
#include <hip/hip_runtime.h>

// ---------------------------------------------------------------------------
// TEN_Encoder: B=8 T=2048 D=512 C=4 K=16 L=6.
// MFMA GEMMs (f16, fp32 acc) with double-buffered LDS + prefetch-before-
// compute (T3 minimum 2-phase).  Scan path + mix_ln + LNs in fp32.
// ---------------------------------------------------------------------------

#define BB 8
#define TT 2048
#define DD 512
#define LL 6
#define MM_ROWS 16384
#define SCHUNK 64
#define NCHUNK 32

typedef __attribute__((ext_vector_type(4))) float f32x4;
typedef __attribute__((ext_vector_type(8))) _Float16 f16x8;
typedef __attribute__((ext_vector_type(4))) _Float16 f16x4;

#define GLOAD16(g, l)                                                          \
  __builtin_amdgcn_global_load_lds(                                            \
      (const __attribute__((address_space(1))) void*)(g),                      \
      (__attribute__((address_space(3))) void*)(l), 16, 0, 0)

__device__ inline void wred2(float& a, float& b) {
#pragma unroll
  for (int off = 32; off; off >>= 1) {
    a += __shfl_xor(a, off);
    b += __shfl_xor(b, off);
  }
}

// ---------------------------------------------------------------------------
// fp32 -> f16 convert (RNE), 4 elems/thread
// ---------------------------------------------------------------------------
__global__ __launch_bounds__(256) void to_half(const float* __restrict__ s,
                                               _Float16* __restrict__ d, int n4) {
  int i = blockIdx.x * 256 + threadIdx.x;
  if (i < n4) {
    f32x4 v = *((const f32x4*)s + i);
    f16x4 o;
#pragma unroll
    for (int q = 0; q < 4; ++q) o[q] = (_Float16)v[q];
    *((f16x4*)d + i) = o;
  }
}

// ---------------------------------------------------------------------------
// Weight prep (fp32)
// ---------------------------------------------------------------------------
__global__ __launch_bounds__(256) void fold_cwin(const float* __restrict__ cWin,
                                                 const float* __restrict__ R,
                                                 float* __restrict__ cWinR) {
  int bid = blockIdx.x;            // (l*4+c)*16 + j, 384 blocks
  int j = bid & 15, lc = bid >> 4;
  int l = lc >> 2;
  for (int d = threadIdx.x; d < DD; d += 256) {
    float s = 0.f;
#pragma unroll
    for (int k = 0; k < 16; ++k)
      s += cWin[(lc * 16 + k) * DD + d] * R[(lc * 16 + k) * 16 + j];
    cWinR[((size_t)l * 64 + (lc & 3) * 16 + j) * DD + d] = s;
  }
}

__global__ __launch_bounds__(256) void transpose_wout(const float* __restrict__ Wout,
                                                      float* __restrict__ WoutT) {
  int bid = blockIdx.x;            // lc*16 + k, 384 blocks
  int k = bid & 15, lc = bid >> 4;
  for (int d = threadIdx.x; d < DD; d += 256)
    WoutT[(size_t)bid * DD + d] = Wout[((size_t)lc * DD + d) * 16 + k];
}

__global__ __launch_bounds__(256) void build_M(const float* __restrict__ alpha,
                                               const float* __restrict__ omega,
                                               const float* __restrict__ R,
                                               float* __restrict__ Mall) {
  int lc = blockIdx.x;             // 24 blocks
  int tid = threadIdx.x;           // k*16+j
  int k = tid >> 4;
  float a = alpha[lc * 16 + k];
  float mag = 1.f / (1.f + expf(-a));
  float om = omega[lc * 16 + k];
  float rr = R[(lc * 16 + k) * 16 + (tid & 15)];
  Mall[lc * 512 + tid] = mag * cosf(om) * rr;
  Mall[lc * 512 + 256 + tid] = mag * sinf(om) * rr;
}

__global__ __launch_bounds__(256) void matpow(const float* __restrict__ M,
                                              float* __restrict__ MS) {
  __shared__ float cr[256], ci[256];
  int lc = blockIdx.x, tid = threadIdx.x;
  cr[tid] = M[lc * 512 + tid];
  ci[tid] = M[lc * 512 + 256 + tid];
  __syncthreads();
  int k = tid >> 4, j = tid & 15;
  for (int it = 0; it < 6; ++it) {
    float sr = 0.f, si = 0.f;
#pragma unroll
    for (int m = 0; m < 16; ++m) {
      float ar = cr[k * 16 + m], ai = ci[k * 16 + m];
      float br = cr[m * 16 + j], bi = ci[m * 16 + j];
      sr += ar * br - ai * bi;
      si += ar * bi + ai * br;
    }
    __syncthreads();
    cr[tid] = sr; ci[tid] = si;
    __syncthreads();
  }
  MS[lc * 512 + tid] = cr[tid];
  MS[lc * 512 + 256 + tid] = ci[tid];
}

// ---------------------------------------------------------------------------
// f16 MFMA GEMM: out(fp32) = A(MxK,f16) * W(NxK,f16)^T + epilogue.
// 128x128 tile, BK=32, 4 waves x (64x64), dbuf LDS + prefetch (2-phase).
// EPI: 1 = +bias ; 2 = +bias +pos[row%T]
// ---------------------------------------------------------------------------
template <int EPI>
__global__ __launch_bounds__(256) void mgemm(const _Float16* __restrict__ A,
                                             const _Float16* __restrict__ W,
                                             const float* __restrict__ bias,
                                             const float* __restrict__ pos,
                                             float* __restrict__ out,
                                             int M, int N, int K) {
  __shared__ alignas(16) _Float16 As[2][4][128][8];
  __shared__ alignas(16) _Float16 Bs[2][4][128][8];
  const int tid = threadIdx.x;
  const int wv = tid >> 6, lane = tid & 63;
  const int m0 = blockIdx.y << 7, n0 = blockIdx.x << 7;
  const int wr = (wv >> 1) << 6, wc = (wv & 1) << 6;
  const int r16 = lane & 15, half = lane >> 4;
  const _Float16* Ap = A + (size_t)(m0 + (tid & 127)) * K + ((tid >> 7) << 3);
  const _Float16* Wp = W + (size_t)(n0 + (tid & 127)) * K + ((tid >> 7) << 3);
  const int lbase = wv << 10;
  f32x4 acc[4][4] = {};

#define MSTAGE(buf, kk)                                                        \
  {                                                                            \
    GLOAD16(Ap + (kk), (char*)As[buf] + lbase);                                \
    GLOAD16(Ap + (kk) + 16, (char*)As[buf] + lbase + 4096);                    \
    GLOAD16(Wp + (kk), (char*)Bs[buf] + lbase);                                \
    GLOAD16(Wp + (kk) + 16, (char*)Bs[buf] + lbase + 4096);                    \
  }

  MSTAGE(0, 0);
  __syncthreads();
  const int nt = K >> 5;
  int cur = 0;
  for (int t = 0; t < nt; ++t) {
    if (t + 1 < nt) MSTAGE(cur ^ 1, (t + 1) << 5);
    f16x8 af[4], bfv[4];
#pragma unroll
    for (int i = 0; i < 4; ++i)
      af[i] = *(const f16x8*)&As[cur][half][wr + (i << 4) + r16][0];
#pragma unroll
    for (int j = 0; j < 4; ++j)
      bfv[j] = *(const f16x8*)&Bs[cur][half][wc + (j << 4) + r16][0];
#pragma unroll
    for (int i = 0; i < 4; ++i)
#pragma unroll
      for (int j = 0; j < 4; ++j)
        acc[i][j] = __builtin_amdgcn_mfma_f32_16x16x32_f16(af[i], bfv[j], acc[i][j], 0, 0, 0);
    __syncthreads();
    cur ^= 1;
  }
#undef MSTAGE
#pragma unroll
  for (int i = 0; i < 4; ++i)
#pragma unroll
    for (int j = 0; j < 4; ++j) {
      int n = n0 + wc + (j << 4) + r16;
      float bv = bias ? bias[n] : 0.f;
#pragma unroll
      for (int r = 0; r < 4; ++r) {
        int m = m0 + wr + (i << 4) + (half << 2) + r;
        float v = acc[i][j][r] + bv;
        if (EPI == 2) v += pos[(size_t)(m & (TT - 1)) * DD + n];
        out[(size_t)m * N + n] = v;
      }
    }
}

// Fused gate/up f16 MFMA GEMM: P(f16) = silu(A*Wg^T+bg) * (A*Wu^T+bu).
// 128x64 tile, 4 waves x (64x32), dbuf + prefetch.  M=16384,N=1024,K=512.
__global__ __launch_bounds__(256) void mgemm_gateup(const _Float16* __restrict__ A,
                                                    const _Float16* __restrict__ Wg,
                                                    const _Float16* __restrict__ Wu,
                                                    const float* __restrict__ bg,
                                                    const float* __restrict__ bu,
                                                    _Float16* __restrict__ P) {
  __shared__ alignas(16) _Float16 As[2][4][128][8];
  __shared__ alignas(16) _Float16 Gs[2][4][64][8];
  __shared__ alignas(16) _Float16 Us[2][4][64][8];
  const int tid = threadIdx.x;
  const int wv = tid >> 6, lane = tid & 63;
  const int m0 = blockIdx.y << 7, n0 = blockIdx.x << 6;
  const int wr = (wv >> 1) << 6, wc = (wv & 1) << 5;
  const int r16 = lane & 15, half = lane >> 4;
  const _Float16* Ap = A + (size_t)(m0 + (tid & 127)) * 512 + ((tid >> 7) << 3);
  const _Float16* Gp = Wg + (size_t)(n0 + (tid & 63)) * 512 + ((tid >> 6) << 3);
  const _Float16* Up = Wu + (size_t)(n0 + (tid & 63)) * 512 + ((tid >> 6) << 3);
  const int lbase = wv << 10;
  f32x4 accg[4][2] = {}, accu[4][2] = {};

#define GSTAGE(buf, kk)                                                        \
  {                                                                            \
    GLOAD16(Ap + (kk), (char*)As[buf] + lbase);                                \
    GLOAD16(Ap + (kk) + 16, (char*)As[buf] + lbase + 4096);                    \
    GLOAD16(Gp + (kk), (char*)Gs[buf] + lbase);                                \
    GLOAD16(Up + (kk), (char*)Us[buf] + lbase);                                \
  }

  GSTAGE(0, 0);
  __syncthreads();
  int cur = 0;
  for (int t = 0; t < 16; ++t) {
    if (t + 1 < 16) GSTAGE(cur ^ 1, (t + 1) << 5);
    f16x8 af[4], gf[2], uf[2];
#pragma unroll
    for (int i = 0; i < 4; ++i)
      af[i] = *(const f16x8*)&As[cur][half][wr + (i << 4) + r16][0];
#pragma unroll
    for (int j = 0; j < 2; ++j) {
      gf[j] = *(const f16x8*)&Gs[cur][half][wc + (j << 4) + r16][0];
      uf[j] = *(const f16x8*)&Us[cur][half][wc + (j << 4) + r16][0];
    }
#pragma unroll
    for (int i = 0; i < 4; ++i)
#pragma unroll
      for (int j = 0; j < 2; ++j) {
        accg[i][j] = __builtin_amdgcn_mfma_f32_16x16x32_f16(af[i], gf[j], accg[i][j], 0, 0, 0);
        accu[i][j] = __builtin_amdgcn_mfma_f32_16x16x32_f16(af[i], uf[j], accu[i][j], 0, 0, 0);
      }
    __syncthreads();
    cur ^= 1;
  }
#undef GSTAGE
#pragma unroll
  for (int i = 0; i < 4; ++i)
#pragma unroll
    for (int j = 0; j < 2; ++j) {
      int n = n0 + wc + (j << 4) + r16;
      float bgv = bg[n], buv = bu[n];
#pragma unroll
      for (int r = 0; r < 4; ++r) {
        int m = m0 + wr + (i << 4) + (half << 2) + r;
        float g = accg[i][j][r] + bgv;
        float u = accu[i][j][r] + buv;
        float sg = g / (1.f + expf(-g));
        P[(size_t)m * 1024 + n] = (_Float16)(sg * u);
      }
    }
}

// ---------------------------------------------------------------------------
// fp32 GEMM (cWin proj, N=64): out = A*W^T, scatter to scan layout
// ---------------------------------------------------------------------------
__global__ __launch_bounds__(256) void gemm_cwin(const float* __restrict__ A,
                                                 const float* __restrict__ W,
                                                 float* __restrict__ out,
                                                 int K) {
  __shared__ float As[16][68];
  __shared__ float Ws[16][68];
  const int tid = threadIdx.x;
  const int tx = tid & 15, ty = tid >> 4;
  const int m0 = blockIdx.y * 64, n0 = blockIdx.x * 64;
  const int lr = tid >> 2, lc = (tid & 3) << 2;
  const float* Ap = A + (size_t)(m0 + lr) * K + lc;
  const float* Wp = W + (size_t)(n0 + lr) * K + lc;
  float acc[4][4] = {};
  for (int k0 = 0; k0 < K; k0 += 16) {
    f32x4 av = *(const f32x4*)(Ap + k0);
    f32x4 wv = *(const f32x4*)(Wp + k0);
    __syncthreads();
#pragma unroll
    for (int q = 0; q < 4; ++q) {
      As[lc + q][lr] = av[q];
      Ws[lc + q][lr] = wv[q];
    }
    __syncthreads();
#pragma unroll
    for (int kk = 0; kk < 16; ++kk) {
      f32x4 a4 = *(const f32x4*)&As[kk][ty * 4];
      f32x4 w4 = *(const f32x4*)&Ws[kk][tx * 4];
#pragma unroll
      for (int i = 0; i < 4; ++i)
#pragma unroll
        for (int j = 0; j < 4; ++j)
          acc[i][j] = fmaf(a4[i], w4[j], acc[i][j]);
    }
  }
#pragma unroll
  for (int i = 0; i < 4; ++i) {
    int m = m0 + ty * 4 + i;
#pragma unroll
    for (int j = 0; j < 4; ++j) {
      int n = n0 + tx * 4 + j;
      int t = m & (TT - 1), b = m >> 11, cc = n >> 4, jj = n & 15;
      out[((size_t)t * 32 + cc * 8 + b) * 16 + jj] = acc[i][j];
    }
  }
}

// ---------------------------------------------------------------------------
// Chunked linear scan (fp32)
// ---------------------------------------------------------------------------
#define SCAN_STEP(uv)                                                          \
  {                                                                            \
    float nr0 = (uv), nr1 = 0.f, ni0 = 0.f, ni1 = 0.f;                         \
    _Pragma("unroll") for (int k = 0; k < 16; k += 2) {                        \
      float rka = __shfl(zr, sb | k), ika = __shfl(zi, sb | k);                \
      float rkb = __shfl(zr, sb | (k + 1)), ikb = __shfl(zi, sb | (k + 1));    \
      nr0 = fmaf(rka, Mr[k], nr0);  nr0 = fmaf(-ika, Mi[k], nr0);              \
      ni0 = fmaf(rka, Mi[k], ni0);  ni0 = fmaf(ika, Mr[k], ni0);               \
      nr1 = fmaf(rkb, Mr[k + 1], nr1); nr1 = fmaf(-ikb, Mi[k + 1], nr1);       \
      ni1 = fmaf(rkb, Mi[k + 1], ni1); ni1 = fmaf(ikb, Mr[k + 1], ni1);        \
    }                                                                          \
    zr = nr0 + nr1; zi = ni0 + ni1;                                            \
  }

__global__ __launch_bounds__(64) void scanA(const float* __restrict__ u,
                                            const float* __restrict__ M,
                                            float* __restrict__ E) {
  int unit = blockIdx.x * 4 + (threadIdx.x >> 4);
  int j = threadIdx.x & 15;
  int sb = threadIdx.x & 48;
  int g = unit >> 5, cb = unit & 31, c = cb >> 3;
  float Mr[16], Mi[16];
  const float* Mc = M + c * 512;
#pragma unroll
  for (int k = 0; k < 16; ++k) { Mr[k] = Mc[k * 16 + j]; Mi[k] = Mc[256 + k * 16 + j]; }
  float zr = 0.f, zi = 0.f;
  const float* up = u + ((size_t)g * SCHUNK * 32 + cb) * 16 + j;
  for (int s = 0; s < SCHUNK; ++s) {
    float uv = up[(size_t)s * 512];
    SCAN_STEP(uv);
  }
  float* Ep = E + ((size_t)unit * 16 + j) * 2;
  Ep[0] = zr; Ep[1] = zi;
}

__global__ __launch_bounds__(512) void scanB(const float* __restrict__ E,
                                             const float* __restrict__ MS,
                                             float* __restrict__ CI) {
  int cb = threadIdx.x >> 4, j = threadIdx.x & 15, sb = threadIdx.x & 48;
  int c = cb >> 3;
  float Mr[16], Mi[16];
  const float* Mc = MS + c * 512;
#pragma unroll
  for (int k = 0; k < 16; ++k) { Mr[k] = Mc[k * 16 + j]; Mi[k] = Mc[256 + k * 16 + j]; }
  float zr = 0.f, zi = 0.f;
  for (int g = 0; g < NCHUNK; ++g) {
    float* cp = CI + (((size_t)g * 32 + cb) * 16 + j) * 2;
    cp[0] = zr; cp[1] = zi;
    const float* ep = E + (((size_t)g * 32 + cb) * 16 + j) * 2;
    float er = ep[0], ei = ep[1];
    SCAN_STEP(er);
    zi += ei;
  }
}

__global__ __launch_bounds__(64) void scanC(const float* __restrict__ u,
                                            const float* __restrict__ M,
                                            const float* __restrict__ CI,
                                            float* __restrict__ rs) {
  int unit = blockIdx.x * 4 + (threadIdx.x >> 4);
  int j = threadIdx.x & 15;
  int sb = threadIdx.x & 48;
  int g = unit >> 5, cb = unit & 31, c = cb >> 3, b = cb & 7;
  float Mr[16], Mi[16];
  const float* Mc = M + c * 512;
#pragma unroll
  for (int k = 0; k < 16; ++k) { Mr[k] = Mc[k * 16 + j]; Mi[k] = Mc[256 + k * 16 + j]; }
  const float* cp = CI + ((size_t)unit * 16 + j) * 2;
  float zr = cp[0], zi = cp[1];
  int t0 = g * SCHUNK;
  const float* up = u + ((size_t)t0 * 32 + cb) * 16 + j;
  float* rp = rs + (((size_t)b * TT + t0) * 4 + c) * 16 + j;
  for (int s = 0; s < SCHUNK; ++s) {
    float uv = up[(size_t)s * 512];
    SCAN_STEP(uv);
    rp[(size_t)s * 64] = zr;
  }
}

// ---------------------------------------------------------------------------
// Fused: cell_out proj + per-cell LN + mean + residual + LN1.
// ---------------------------------------------------------------------------
__global__ __launch_bounds__(256) void mix_ln(const float* __restrict__ rs,
                                              const float* __restrict__ WoutT,
                                              const float* __restrict__ bo,
                                              const float* __restrict__ cg,
                                              const float* __restrict__ cbv,
                                              const float* __restrict__ h,
                                              const float* __restrict__ g1,
                                              const float* __restrict__ b1v,
                                              float* __restrict__ h1,
                                              _Float16* __restrict__ h1b) {
  int wave = threadIdx.x >> 6, lane = threadIdx.x & 63;
  int row0 = blockIdx.x * 16 + wave * 4;
  float rsv[4];
#pragma unroll
  for (int r = 0; r < 4; ++r) rsv[r] = rs[(size_t)(row0 + r) * 64 + lane];
  float mixed[4][8];
#pragma unroll
  for (int r = 0; r < 4; ++r)
#pragma unroll
    for (int q = 0; q < 8; ++q) mixed[r][q] = 0.f;
  for (int c = 0; c < 4; ++c) {
    float v[4][8];
#pragma unroll
    for (int r = 0; r < 4; ++r)
#pragma unroll
      for (int q = 0; q < 8; ++q) v[r][q] = 0.f;
#pragma unroll
    for (int k = 0; k < 16; ++k) {
      float w[8];
#pragma unroll
      for (int q = 0; q < 8; ++q) w[q] = WoutT[(size_t)(c * 16 + k) * DD + q * 64 + lane];
#pragma unroll
      for (int r = 0; r < 4; ++r) {
        float rv = __shfl(rsv[r], c * 16 + k);
#pragma unroll
        for (int q = 0; q < 8; ++q) v[r][q] = fmaf(rv, w[q], v[r][q]);
      }
    }
    float bvv[8], gv[8], bb[8];
#pragma unroll
    for (int q = 0; q < 8; ++q) {
      bvv[q] = bo[c * DD + q * 64 + lane];
      gv[q] = cg[c * DD + q * 64 + lane];
      bb[q] = cbv[c * DD + q * 64 + lane];
    }
#pragma unroll
    for (int r = 0; r < 4; ++r) {
      float s = 0.f, s2 = 0.f;
#pragma unroll
      for (int q = 0; q < 8; ++q) {
        float xv = v[r][q] + bvv[q];
        v[r][q] = xv; s += xv; s2 += xv * xv;
      }
      wred2(s, s2);
      float mean = s * (1.f / 512.f);
      float inv = rsqrtf(s2 * (1.f / 512.f) - mean * mean + 1e-5f);
#pragma unroll
      for (int q = 0; q < 8; ++q)
        mixed[r][q] += ((v[r][q] - mean) * inv * gv[q] + bb[q]) * 0.25f;
    }
  }
  float gg[8], gb[8];
#pragma unroll
  for (int q = 0; q < 8; ++q) { gg[q] = g1[q * 64 + lane]; gb[q] = b1v[q * 64 + lane]; }
#pragma unroll
  for (int r = 0; r < 4; ++r) {
    float xv[8]; float s = 0.f, s2 = 0.f;
#pragma unroll
    for (int q = 0; q < 8; ++q) {
      float t = h[(size_t)(row0 + r) * DD + q * 64 + lane] + mixed[r][q];
      xv[q] = t; s += t; s2 += t * t;
    }
    wred2(s, s2);
    float mean = s * (1.f / 512.f);
    float inv = rsqrtf(s2 * (1.f / 512.f) - mean * mean + 1e-5f);
#pragma unroll
    for (int q = 0; q < 8; ++q) {
      float val = (xv[q] - mean) * inv * gg[q] + gb[q];
      h1[(size_t)(row0 + r) * DD + q * 64 + lane] = val;
      h1b[(size_t)(row0 + r) * DD + q * 64 + lane] = (_Float16)val;
    }
  }
}

// out_row = LN(a_row (+ r_row)) * g + b.  One wave per row.
template <int RES>
__global__ __launch_bounds__(256) void ln_res(const float* __restrict__ a,
                                              const float* __restrict__ rr,
                                              const float* __restrict__ g,
                                              const float* __restrict__ b,
                                              float* __restrict__ o) {
  int wave = threadIdx.x >> 6, lane = threadIdx.x & 63;
  int row = blockIdx.x * 4 + wave;
  float xv[8]; float s = 0.f, s2 = 0.f;
#pragma unroll
  for (int q = 0; q < 8; ++q) {
    float t = a[(size_t)row * DD + q * 64 + lane];
    if (RES) t += rr[(size_t)row * DD + q * 64 + lane];
    xv[q] = t; s += t; s2 += t * t;
  }
  wred2(s, s2);
  float mean = s * (1.f / 512.f);
  float inv = rsqrtf(s2 * (1.f / 512.f) - mean * mean + 1e-5f);
#pragma unroll
  for (int q = 0; q < 8; ++q)
    o[(size_t)row * DD + q * 64 + lane] = (xv[q] - mean) * inv * g[q * 64 + lane] + b[q * 64 + lane];
}

// ---------------------------------------------------------------------------
// Pooling + head
// ---------------------------------------------------------------------------
__global__ __launch_bounds__(256) void pool1(const float* __restrict__ h,
                                             float* __restrict__ part) {
  int b = blockIdx.y, tc = blockIdx.x;   // grid (16,8)
  for (int d = threadIdx.x; d < DD; d += 256) {
    float s = 0.f;
    for (int t = tc * 128; t < (tc + 1) * 128; ++t)
      s += h[((size_t)b * TT + t) * DD + d];
    part[(size_t)(b * 16 + tc) * DD + d] = s;
  }
}

__global__ __launch_bounds__(512) void pool2(const float* __restrict__ part,
                                             float* __restrict__ pooled) {
  int b = blockIdx.x;
  int d = threadIdx.x;
  float s = 0.f;
#pragma unroll
  for (int tc = 0; tc < 16; ++tc) s += part[(size_t)(b * 16 + tc) * DD + d];
  pooled[(size_t)b * DD + d] = s * (1.f / 2048.f);
}

__global__ __launch_bounds__(256) void head1(const float* __restrict__ pooled,
                                             const float* __restrict__ W1,
                                             const float* __restrict__ b1,
                                             float* __restrict__ hid) {
  int b = blockIdx.x, n = threadIdx.x;
  float s = b1[n];
  for (int d = 0; d < DD; ++d) s += pooled[(size_t)b * DD + d] * W1[(size_t)n * DD + d];
  hid[(size_t)b * 256 + n] = 0.5f * s * (1.f + erff(s * 0.7071067811865475f));
}

__global__ __launch_bounds__(64) void head2(const float* __restrict__ hid,
                                            const float* __restrict__ W2,
                                            const float* __restrict__ b2,
                                            float* __restrict__ out) {
  int b = blockIdx.x, lane = threadIdx.x;
  float a0 = 0.f, a1 = 0.f;
#pragma unroll
  for (int q = 0; q < 4; ++q) {
    int n = lane + q * 64;
    float hv = hid[(size_t)b * 256 + n];
    a0 = fmaf(hv, W2[n], a0);
    a1 = fmaf(hv, W2[256 + n], a1);
  }
  wred2(a0, a1);
  if (lane == 0) {
    out[b * 2 + 0] = a0 + b2[0];
    out[b * 2 + 1] = a1 + b2[1];
  }
}

// ---------------------------------------------------------------------------
// Launch
// ---------------------------------------------------------------------------
extern "C" void kernel_launch(void* const* d_in, const int* in_sizes, int n_in,
                              void* d_out, int out_size, void* d_ws, size_t ws_size,
                              hipStream_t stream) {
  const float* x    = (const float*)d_in[0];
  const float* Win  = (const float*)d_in[1];
  const float* bin_ = (const float*)d_in[2];
  const float* pos  = (const float*)d_in[3];
  const float* alpha= (const float*)d_in[4];
  const float* omega= (const float*)d_in[5];
  const float* cWin = (const float*)d_in[6];
  const float* R    = (const float*)d_in[7];
  const float* Wout = (const float*)d_in[8];
  const float* bout = (const float*)d_in[9];
  const float* clng = (const float*)d_in[10];
  const float* clnb = (const float*)d_in[11];
  const float* ln1g = (const float*)d_in[12];
  const float* ln1b = (const float*)d_in[13];
  const float* Wg   = (const float*)d_in[14];
  const float* bg   = (const float*)d_in[15];
  const float* Wu   = (const float*)d_in[16];
  const float* bu   = (const float*)d_in[17];
  const float* Wd   = (const float*)d_in[18];
  const float* bd   = (const float*)d_in[19];
  const float* ln2g = (const float*)d_in[20];
  const float* ln2b = (const float*)d_in[21];
  const float* normg= (const float*)d_in[22];
  const float* normb= (const float*)d_in[23];
  const float* W1   = (const float*)d_in[24];
  const float* b1   = (const float*)d_in[25];
  const float* W2   = (const float*)d_in[26];
  const float* b2   = (const float*)d_in[27];
  float* out = (float*)d_out;
  char* ws = (char*)d_ws;

  // workspace layout (bytes)
  float*     H    = (float*)(ws + 0);              // 32 MB fp32
  float*     H1   = (float*)(ws + 33554432);       // 32 MB fp32
  _Float16*  Pb   = (_Float16*)(ws + 67108864);    // 32 MB f16 (16384x1024)
  _Float16*  xb   = (_Float16*)(ws + 67108864);    // alias: dead before Pb used
  float*     U    = (float*)(ws + 67108864);       // alias: dead before gateup
  float*     RS   = (float*)(ws + 71303168);       // alias inside Pb region
  _Float16*  H1b  = (_Float16*)(ws + 100663296);   // 16 MB f16
  float*     CWR  = (float*)(ws + 117440512);      // 768 KB
  float*     WOT  = (float*)(ws + 118226944);      // 768 KB
  _Float16*  Winb = (_Float16*)(ws + 119013376);   // 512 KB
  _Float16*  Wgb  = (_Float16*)(ws + 119537664);   // 6 MB
  _Float16*  Wub  = (_Float16*)(ws + 125829120);   // 6 MB
  _Float16*  Wdb  = (_Float16*)(ws + 132120576);   // 6 MB
  float*     MB   = (float*)(ws + 138412032);      // 48 KB
  float*     MSB  = (float*)(ws + 138461184);      // 48 KB
  float*     E    = (float*)(ws + 138510336);      // 128 KB
  float*     CI   = (float*)(ws + 138641408);      // 128 KB
  float*     PART = (float*)(ws + 138772480);      // 256 KB
  float*     POOL = (float*)(ws + 139034624);      // 16 KB
  float*     HID  = (float*)(ws + 139050496);      // 8 KB

  // f16 weight/input conversion
  hipLaunchKernelGGL(to_half, dim3(8192), dim3(256), 0, stream, x, xb, 2097152);
  hipLaunchKernelGGL(to_half, dim3(256),  dim3(256), 0, stream, Win, Winb, 65536);
  hipLaunchKernelGGL(to_half, dim3(3072), dim3(256), 0, stream, Wg, Wgb, 786432);
  hipLaunchKernelGGL(to_half, dim3(3072), dim3(256), 0, stream, Wu, Wub, 786432);
  hipLaunchKernelGGL(to_half, dim3(3072), dim3(256), 0, stream, Wd, Wdb, 786432);

  // scan weight prep
  hipLaunchKernelGGL(fold_cwin, dim3(384), dim3(256), 0, stream, cWin, R, CWR);
  hipLaunchKernelGGL(transpose_wout, dim3(384), dim3(256), 0, stream, Wout, WOT);
  hipLaunchKernelGGL(build_M, dim3(24), dim3(256), 0, stream, alpha, omega, R, MB);
  hipLaunchKernelGGL(matpow, dim3(24), dim3(256), 0, stream, MB, MSB);

  // input projection + pos emb (f16 MFMA)
  hipLaunchKernelGGL((mgemm<2>), dim3(4, 128), dim3(256), 0, stream,
                     xb, Winb, bin_, pos, H, MM_ROWS, DD, DD);

  for (int l = 0; l < LL; ++l) {
    hipLaunchKernelGGL(gemm_cwin, dim3(1, 256), dim3(256), 0, stream,
                       H, CWR + (size_t)l * 64 * DD, U, DD);
    hipLaunchKernelGGL(scanA, dim3(256), dim3(64), 0, stream, U, MB + l * 2048, E);
    hipLaunchKernelGGL(scanB, dim3(1), dim3(512), 0, stream, E, MSB + l * 2048, CI);
    hipLaunchKernelGGL(scanC, dim3(256), dim3(64), 0, stream, U, MB + l * 2048, CI, RS);
    hipLaunchKernelGGL(mix_ln, dim3(1024), dim3(256), 0, stream,
                       RS, WOT + (size_t)l * 32768, bout + l * 2048,
                       clng + l * 2048, clnb + l * 2048, H,
                       ln1g + l * 512, ln1b + l * 512, H1, H1b);
    hipLaunchKernelGGL(mgemm_gateup, dim3(16, 128), dim3(256), 0, stream,
                       H1b, Wgb + (size_t)l * 524288, Wub + (size_t)l * 524288,
                       bg + l * 1024, bu + l * 1024, Pb);
    hipLaunchKernelGGL((mgemm<1>), dim3(4, 128), dim3(256), 0, stream,
                       Pb, Wdb + (size_t)l * 524288, bd + l * 512,
                       (const float*)nullptr, H, MM_ROWS, DD, 1024);
    hipLaunchKernelGGL((ln_res<1>), dim3(4096), dim3(256), 0, stream,
                       H1, H, ln2g + l * 512, ln2b + l * 512, H);
  }

  hipLaunchKernelGGL((ln_res<0>), dim3(4096), dim3(256), 0, stream,
                     H, (const float*)nullptr, normg, normb, H);
  hipLaunchKernelGGL(pool1, dim3(16, 8), dim3(256), 0, stream, H, PART);
  hipLaunchKernelGGL(pool2, dim3(8), dim3(512), 0, stream, PART, POOL);
  hipLaunchKernelGGL(head1, dim3(8), dim3(256), 0, stream, POOL, W1, b1, HID);
  hipLaunchKernelGGL(head2, dim3(8), dim3(64), 0, stream, HID, W2, b2, out);
}

// Round 4
// 2101.416 us; speedup vs baseline: 2.5168x; 1.0241x over previous
//
#include <hip/hip_runtime.h>

// ---------------------------------------------------------------------------
// TEN_Encoder: B=8 T=2048 D=512 C=4 K=16 L=6.
// MFMA GEMMs (f16, fp32 acc): 3-buffer depth-2 prefetch, raw s_barrier +
// counted vmcnt (never 0 in-loop).  Scan path + mix_ln + LNs in fp32.
// ---------------------------------------------------------------------------

#define BB 8
#define TT 2048
#define DD 512
#define LL 6
#define MM_ROWS 16384
#define SCHUNK 64
#define NCHUNK 32

typedef __attribute__((ext_vector_type(4))) float f32x4;
typedef __attribute__((ext_vector_type(8))) _Float16 f16x8;
typedef __attribute__((ext_vector_type(4))) _Float16 f16x4;

#define GLOAD16(g, l)                                                          \
  __builtin_amdgcn_global_load_lds(                                            \
      (const __attribute__((address_space(1))) void*)(g),                      \
      (__attribute__((address_space(3))) void*)(l), 16, 0, 0)

#define VM4 asm volatile("s_waitcnt vmcnt(4)" ::: "memory")
#define VM3 asm volatile("s_waitcnt vmcnt(3)" ::: "memory")
#define VM0 asm volatile("s_waitcnt vmcnt(0)" ::: "memory")
#define BARRIER() __builtin_amdgcn_s_barrier()

__device__ inline void wred2(float& a, float& b) {
#pragma unroll
  for (int off = 32; off; off >>= 1) {
    a += __shfl_xor(a, off);
    b += __shfl_xor(b, off);
  }
}

// ---------------------------------------------------------------------------
// fp32 -> f16 convert (RNE), 4 elems/thread
// ---------------------------------------------------------------------------
__global__ __launch_bounds__(256) void to_half(const float* __restrict__ s,
                                               _Float16* __restrict__ d, int n4) {
  int i = blockIdx.x * 256 + threadIdx.x;
  if (i < n4) {
    f32x4 v = *((const f32x4*)s + i);
    f16x4 o;
#pragma unroll
    for (int q = 0; q < 4; ++q) o[q] = (_Float16)v[q];
    *((f16x4*)d + i) = o;
  }
}

// ---------------------------------------------------------------------------
// Weight prep
// ---------------------------------------------------------------------------
// cWinR f16: cWinR[l][(c*16+j)][d] = sum_k cWin[l,c,k,d] * R[l,c,k,j]
__global__ __launch_bounds__(256) void fold_cwin(const float* __restrict__ cWin,
                                                 const float* __restrict__ R,
                                                 _Float16* __restrict__ cWinR) {
  int bid = blockIdx.x;            // (l*4+c)*16 + j, 384 blocks
  int j = bid & 15, lc = bid >> 4;
  int l = lc >> 2;
  for (int d = threadIdx.x; d < DD; d += 256) {
    float s = 0.f;
#pragma unroll
    for (int k = 0; k < 16; ++k)
      s += cWin[(lc * 16 + k) * DD + d] * R[(lc * 16 + k) * 16 + j];
    cWinR[((size_t)l * 64 + (lc & 3) * 16 + j) * DD + d] = (_Float16)s;
  }
}

__global__ __launch_bounds__(256) void transpose_wout(const float* __restrict__ Wout,
                                                      float* __restrict__ WoutT) {
  int bid = blockIdx.x;            // lc*16 + k, 384 blocks
  int k = bid & 15, lc = bid >> 4;
  for (int d = threadIdx.x; d < DD; d += 256)
    WoutT[(size_t)bid * DD + d] = Wout[((size_t)lc * DD + d) * 16 + k];
}

__global__ __launch_bounds__(256) void build_M(const float* __restrict__ alpha,
                                               const float* __restrict__ omega,
                                               const float* __restrict__ R,
                                               float* __restrict__ Mall) {
  int lc = blockIdx.x;             // 24 blocks
  int tid = threadIdx.x;           // k*16+j
  int k = tid >> 4;
  float a = alpha[lc * 16 + k];
  float mag = 1.f / (1.f + expf(-a));
  float om = omega[lc * 16 + k];
  float rr = R[(lc * 16 + k) * 16 + (tid & 15)];
  Mall[lc * 512 + tid] = mag * cosf(om) * rr;
  Mall[lc * 512 + 256 + tid] = mag * sinf(om) * rr;
}

__global__ __launch_bounds__(256) void matpow(const float* __restrict__ M,
                                              float* __restrict__ MS) {
  __shared__ float cr[256], ci[256];
  int lc = blockIdx.x, tid = threadIdx.x;
  cr[tid] = M[lc * 512 + tid];
  ci[tid] = M[lc * 512 + 256 + tid];
  __syncthreads();
  int k = tid >> 4, j = tid & 15;
  for (int it = 0; it < 6; ++it) {
    float sr = 0.f, si = 0.f;
#pragma unroll
    for (int m = 0; m < 16; ++m) {
      float ar = cr[k * 16 + m], ai = ci[k * 16 + m];
      float br = cr[m * 16 + j], bi = ci[m * 16 + j];
      sr += ar * br - ai * bi;
      si += ar * bi + ai * br;
    }
    __syncthreads();
    cr[tid] = sr; ci[tid] = si;
    __syncthreads();
  }
  MS[lc * 512 + tid] = cr[tid];
  MS[lc * 512 + 256 + tid] = ci[tid];
}

// ---------------------------------------------------------------------------
// f16 MFMA GEMM: out(fp32) = A(MxK,f16) * W(NxK,f16)^T + epilogue.
// 128x128 tile, BK=32, 4 waves x (64x64).  3-buf depth-2 prefetch, counted
// vmcnt + raw barrier.  EPI: 1 = +bias ; 2 = +bias +pos[row%T].
// HOUT: also write f16 copy to ob.
// ---------------------------------------------------------------------------
template <int EPI, int HOUT>
__global__ __launch_bounds__(256) void mgemm(const _Float16* __restrict__ A,
                                             const _Float16* __restrict__ W,
                                             const float* __restrict__ bias,
                                             const float* __restrict__ pos,
                                             float* __restrict__ out,
                                             _Float16* __restrict__ ob,
                                             int M, int N, int K) {
  __shared__ alignas(16) _Float16 As[3][4][128][8];
  __shared__ alignas(16) _Float16 Bs[3][4][128][8];
  const int tid = threadIdx.x;
  const int wv = tid >> 6, lane = tid & 63;
  const int m0 = blockIdx.y << 7, n0 = blockIdx.x << 7;
  const int wr = (wv >> 1) << 6, wc = (wv & 1) << 6;
  const int r16 = lane & 15, half = lane >> 4;
  const _Float16* Ap = A + (size_t)(m0 + (tid & 127)) * K + ((tid >> 7) << 3);
  const _Float16* Wp = W + (size_t)(n0 + (tid & 127)) * K + ((tid >> 7) << 3);
  const int lbase = wv << 10;
  f32x4 acc[4][4] = {};

#define MSTAGE(buf, kk)                                                        \
  {                                                                            \
    GLOAD16(Ap + (kk), (char*)As[buf] + lbase);                                \
    GLOAD16(Ap + (kk) + 16, (char*)As[buf] + lbase + 4096);                    \
    GLOAD16(Wp + (kk), (char*)Bs[buf] + lbase);                                \
    GLOAD16(Wp + (kk) + 16, (char*)Bs[buf] + lbase + 4096);                    \
  }

  const int nt = K >> 5;
  MSTAGE(0, 0);
  MSTAGE(1, 32);
  int cur = 0, nxt = 2;
  for (int t = 0; t < nt; ++t) {
    if (t + 1 < nt) { VM4; } else { VM0; }
    BARRIER();
    if (t + 2 < nt) MSTAGE(nxt, (t + 2) << 5);
    f16x8 af[4], bfv[4];
#pragma unroll
    for (int i = 0; i < 4; ++i)
      af[i] = *(const f16x8*)&As[cur][half][wr + (i << 4) + r16][0];
#pragma unroll
    for (int j = 0; j < 4; ++j)
      bfv[j] = *(const f16x8*)&Bs[cur][half][wc + (j << 4) + r16][0];
#pragma unroll
    for (int i = 0; i < 4; ++i)
#pragma unroll
      for (int j = 0; j < 4; ++j)
        acc[i][j] = __builtin_amdgcn_mfma_f32_16x16x32_f16(af[i], bfv[j], acc[i][j], 0, 0, 0);
    cur = (cur == 2) ? 0 : cur + 1;
    nxt = (nxt == 2) ? 0 : nxt + 1;
  }
#undef MSTAGE
#pragma unroll
  for (int i = 0; i < 4; ++i)
#pragma unroll
    for (int j = 0; j < 4; ++j) {
      int n = n0 + wc + (j << 4) + r16;
      float bv = bias ? bias[n] : 0.f;
#pragma unroll
      for (int r = 0; r < 4; ++r) {
        int m = m0 + wr + (i << 4) + (half << 2) + r;
        float v = acc[i][j][r] + bv;
        if (EPI == 2) v += pos[(size_t)(m & (TT - 1)) * DD + n];
        out[(size_t)m * N + n] = v;
        if (HOUT) ob[(size_t)m * N + n] = (_Float16)v;
      }
    }
}

// Fused gate/up f16 MFMA GEMM: P(f16) = silu(A*Wg^T+bg) * (A*Wu^T+bu).
// 128x64 tile, 4 waves x (64x32).  M=16384,N=1024,K=512.
__global__ __launch_bounds__(256) void mgemm_gateup(const _Float16* __restrict__ A,
                                                    const _Float16* __restrict__ Wg,
                                                    const _Float16* __restrict__ Wu,
                                                    const float* __restrict__ bg,
                                                    const float* __restrict__ bu,
                                                    _Float16* __restrict__ P) {
  __shared__ alignas(16) _Float16 As[3][4][128][8];
  __shared__ alignas(16) _Float16 Gs[3][4][64][8];
  __shared__ alignas(16) _Float16 Us[3][4][64][8];
  const int tid = threadIdx.x;
  const int wv = tid >> 6, lane = tid & 63;
  const int m0 = blockIdx.y << 7, n0 = blockIdx.x << 6;
  const int wr = (wv >> 1) << 6, wc = (wv & 1) << 5;
  const int r16 = lane & 15, half = lane >> 4;
  const _Float16* Ap = A + (size_t)(m0 + (tid & 127)) * 512 + ((tid >> 7) << 3);
  const _Float16* Gp = Wg + (size_t)(n0 + (tid & 63)) * 512 + ((tid >> 6) << 3);
  const _Float16* Up = Wu + (size_t)(n0 + (tid & 63)) * 512 + ((tid >> 6) << 3);
  const int lbase = wv << 10;
  f32x4 accg[4][2] = {}, accu[4][2] = {};

#define GSTAGE(buf, kk)                                                        \
  {                                                                            \
    GLOAD16(Ap + (kk), (char*)As[buf] + lbase);                                \
    GLOAD16(Ap + (kk) + 16, (char*)As[buf] + lbase + 4096);                    \
    GLOAD16(Gp + (kk), (char*)Gs[buf] + lbase);                                \
    GLOAD16(Up + (kk), (char*)Us[buf] + lbase);                                \
  }

  GSTAGE(0, 0);
  GSTAGE(1, 32);
  int cur = 0, nxt = 2;
  for (int t = 0; t < 16; ++t) {
    if (t + 1 < 16) { VM4; } else { VM0; }
    BARRIER();
    if (t + 2 < 16) GSTAGE(nxt, (t + 2) << 5);
    f16x8 af[4], gf[2], uf[2];
#pragma unroll
    for (int i = 0; i < 4; ++i)
      af[i] = *(const f16x8*)&As[cur][half][wr + (i << 4) + r16][0];
#pragma unroll
    for (int j = 0; j < 2; ++j) {
      gf[j] = *(const f16x8*)&Gs[cur][half][wc + (j << 4) + r16][0];
      uf[j] = *(const f16x8*)&Us[cur][half][wc + (j << 4) + r16][0];
    }
#pragma unroll
    for (int i = 0; i < 4; ++i)
#pragma unroll
      for (int j = 0; j < 2; ++j) {
        accg[i][j] = __builtin_amdgcn_mfma_f32_16x16x32_f16(af[i], gf[j], accg[i][j], 0, 0, 0);
        accu[i][j] = __builtin_amdgcn_mfma_f32_16x16x32_f16(af[i], uf[j], accu[i][j], 0, 0, 0);
      }
    cur = (cur == 2) ? 0 : cur + 1;
    nxt = (nxt == 2) ? 0 : nxt + 1;
  }
#undef GSTAGE
#pragma unroll
  for (int i = 0; i < 4; ++i)
#pragma unroll
    for (int j = 0; j < 2; ++j) {
      int n = n0 + wc + (j << 4) + r16;
      float bgv = bg[n], buv = bu[n];
#pragma unroll
      for (int r = 0; r < 4; ++r) {
        int m = m0 + wr + (i << 4) + (half << 2) + r;
        float g = accg[i][j][r] + bgv;
        float u = accu[i][j][r] + buv;
        float sg = g / (1.f + expf(-g));
        P[(size_t)m * 1024 + n] = (_Float16)(sg * u);
      }
    }
}

// cWin projection f16 MFMA: u = Hb(16384x512) * cWinR(64x512)^T, scatter to
// scan layout u[t][cb][j].  128x64 tile, 4 waves x (64x32).  L=3 loads/thr.
__global__ __launch_bounds__(256) void cwin16(const _Float16* __restrict__ A,
                                              const _Float16* __restrict__ W,
                                              float* __restrict__ u) {
  __shared__ alignas(16) _Float16 As[3][4][128][8];
  __shared__ alignas(16) _Float16 Ws[3][4][64][8];
  const int tid = threadIdx.x;
  const int wv = tid >> 6, lane = tid & 63;
  const int m0 = blockIdx.y << 7;
  const int wr = (wv >> 1) << 6, wc = (wv & 1) << 5;
  const int r16 = lane & 15, half = lane >> 4;
  const _Float16* Ap = A + (size_t)(m0 + (tid & 127)) * 512 + ((tid >> 7) << 3);
  const _Float16* Wp = W + (size_t)(tid & 63) * 512 + ((tid >> 6) << 3);
  const int lbase = wv << 10;
  f32x4 acc[4][2] = {};

#define CSTAGE(buf, kk)                                                        \
  {                                                                            \
    GLOAD16(Ap + (kk), (char*)As[buf] + lbase);                                \
    GLOAD16(Ap + (kk) + 16, (char*)As[buf] + lbase + 4096);                    \
    GLOAD16(Wp + (kk), (char*)Ws[buf] + lbase);                                \
  }

  CSTAGE(0, 0);
  CSTAGE(1, 32);
  int cur = 0, nxt = 2;
  for (int t = 0; t < 16; ++t) {
    if (t + 1 < 16) { VM3; } else { VM0; }
    BARRIER();
    if (t + 2 < 16) CSTAGE(nxt, (t + 2) << 5);
    f16x8 af[4], wf[2];
#pragma unroll
    for (int i = 0; i < 4; ++i)
      af[i] = *(const f16x8*)&As[cur][half][wr + (i << 4) + r16][0];
#pragma unroll
    for (int j = 0; j < 2; ++j)
      wf[j] = *(const f16x8*)&Ws[cur][half][wc + (j << 4) + r16][0];
#pragma unroll
    for (int i = 0; i < 4; ++i)
#pragma unroll
      for (int j = 0; j < 2; ++j)
        acc[i][j] = __builtin_amdgcn_mfma_f32_16x16x32_f16(af[i], wf[j], acc[i][j], 0, 0, 0);
    cur = (cur == 2) ? 0 : cur + 1;
    nxt = (nxt == 2) ? 0 : nxt + 1;
  }
#undef CSTAGE
#pragma unroll
  for (int i = 0; i < 4; ++i)
#pragma unroll
    for (int j = 0; j < 2; ++j) {
      int n = wc + (j << 4) + r16;
      int c = n >> 4, jj = n & 15;
#pragma unroll
      for (int r = 0; r < 4; ++r) {
        int m = m0 + wr + (i << 4) + (half << 2) + r;
        int t = m & (TT - 1), b = m >> 11;
        u[((size_t)t * 32 + c * 8 + b) * 16 + jj] = acc[i][j][r];
      }
    }
}

// ---------------------------------------------------------------------------
// Chunked linear scan (fp32)
// ---------------------------------------------------------------------------
#define SCAN_STEP(uv)                                                          \
  {                                                                            \
    float nr0 = (uv), nr1 = 0.f, ni0 = 0.f, ni1 = 0.f;                         \
    _Pragma("unroll") for (int k = 0; k < 16; k += 2) {                        \
      float rka = __shfl(zr, sb | k), ika = __shfl(zi, sb | k);                \
      float rkb = __shfl(zr, sb | (k + 1)), ikb = __shfl(zi, sb | (k + 1));    \
      nr0 = fmaf(rka, Mr[k], nr0);  nr0 = fmaf(-ika, Mi[k], nr0);              \
      ni0 = fmaf(rka, Mi[k], ni0);  ni0 = fmaf(ika, Mr[k], ni0);               \
      nr1 = fmaf(rkb, Mr[k + 1], nr1); nr1 = fmaf(-ikb, Mi[k + 1], nr1);       \
      ni1 = fmaf(rkb, Mi[k + 1], ni1); ni1 = fmaf(ikb, Mr[k + 1], ni1);        \
    }                                                                          \
    zr = nr0 + nr1; zi = ni0 + ni1;                                            \
  }

__global__ __launch_bounds__(64) void scanA(const float* __restrict__ u,
                                            const float* __restrict__ M,
                                            float* __restrict__ E) {
  int unit = blockIdx.x * 4 + (threadIdx.x >> 4);
  int j = threadIdx.x & 15;
  int sb = threadIdx.x & 48;
  int g = unit >> 5, cb = unit & 31, c = cb >> 3;
  float Mr[16], Mi[16];
  const float* Mc = M + c * 512;
#pragma unroll
  for (int k = 0; k < 16; ++k) { Mr[k] = Mc[k * 16 + j]; Mi[k] = Mc[256 + k * 16 + j]; }
  float zr = 0.f, zi = 0.f;
  const float* up = u + ((size_t)g * SCHUNK * 32 + cb) * 16 + j;
  for (int s = 0; s < SCHUNK; ++s) {
    float uv = up[(size_t)s * 512];
    SCAN_STEP(uv);
  }
  float* Ep = E + ((size_t)unit * 16 + j) * 2;
  Ep[0] = zr; Ep[1] = zi;
}

__global__ __launch_bounds__(512) void scanB(const float* __restrict__ E,
                                             const float* __restrict__ MS,
                                             float* __restrict__ CI) {
  int cb = threadIdx.x >> 4, j = threadIdx.x & 15, sb = threadIdx.x & 48;
  int c = cb >> 3;
  float Mr[16], Mi[16];
  const float* Mc = MS + c * 512;
#pragma unroll
  for (int k = 0; k < 16; ++k) { Mr[k] = Mc[k * 16 + j]; Mi[k] = Mc[256 + k * 16 + j]; }
  float zr = 0.f, zi = 0.f;
  for (int g = 0; g < NCHUNK; ++g) {
    float* cp = CI + (((size_t)g * 32 + cb) * 16 + j) * 2;
    cp[0] = zr; cp[1] = zi;
    const float* ep = E + (((size_t)g * 32 + cb) * 16 + j) * 2;
    float er = ep[0], ei = ep[1];
    SCAN_STEP(er);
    zi += ei;
  }
}

__global__ __launch_bounds__(64) void scanC(const float* __restrict__ u,
                                            const float* __restrict__ M,
                                            const float* __restrict__ CI,
                                            float* __restrict__ rs) {
  int unit = blockIdx.x * 4 + (threadIdx.x >> 4);
  int j = threadIdx.x & 15;
  int sb = threadIdx.x & 48;
  int g = unit >> 5, cb = unit & 31, c = cb >> 3, b = cb & 7;
  float Mr[16], Mi[16];
  const float* Mc = M + c * 512;
#pragma unroll
  for (int k = 0; k < 16; ++k) { Mr[k] = Mc[k * 16 + j]; Mi[k] = Mc[256 + k * 16 + j]; }
  const float* cp = CI + ((size_t)unit * 16 + j) * 2;
  float zr = cp[0], zi = cp[1];
  int t0 = g * SCHUNK;
  const float* up = u + ((size_t)t0 * 32 + cb) * 16 + j;
  float* rp = rs + (((size_t)b * TT + t0) * 4 + c) * 16 + j;
  for (int s = 0; s < SCHUNK; ++s) {
    float uv = up[(size_t)s * 512];
    SCAN_STEP(uv);
    rp[(size_t)s * 64] = zr;
  }
}

// ---------------------------------------------------------------------------
// Fused: cell_out proj + per-cell LN + mean + residual + LN1.
// ---------------------------------------------------------------------------
__global__ __launch_bounds__(256) void mix_ln(const float* __restrict__ rs,
                                              const float* __restrict__ WoutT,
                                              const float* __restrict__ bo,
                                              const float* __restrict__ cg,
                                              const float* __restrict__ cbv,
                                              const float* __restrict__ h,
                                              const float* __restrict__ g1,
                                              const float* __restrict__ b1v,
                                              float* __restrict__ h1,
                                              _Float16* __restrict__ h1b) {
  int wave = threadIdx.x >> 6, lane = threadIdx.x & 63;
  int row0 = blockIdx.x * 16 + wave * 4;
  float rsv[4];
#pragma unroll
  for (int r = 0; r < 4; ++r) rsv[r] = rs[(size_t)(row0 + r) * 64 + lane];
  float mixed[4][8];
#pragma unroll
  for (int r = 0; r < 4; ++r)
#pragma unroll
    for (int q = 0; q < 8; ++q) mixed[r][q] = 0.f;
  for (int c = 0; c < 4; ++c) {
    float v[4][8];
#pragma unroll
    for (int r = 0; r < 4; ++r)
#pragma unroll
      for (int q = 0; q < 8; ++q) v[r][q] = 0.f;
#pragma unroll
    for (int k = 0; k < 16; ++k) {
      float w[8];
#pragma unroll
      for (int q = 0; q < 8; ++q) w[q] = WoutT[(size_t)(c * 16 + k) * DD + q * 64 + lane];
#pragma unroll
      for (int r = 0; r < 4; ++r) {
        float rv = __shfl(rsv[r], c * 16 + k);
#pragma unroll
        for (int q = 0; q < 8; ++q) v[r][q] = fmaf(rv, w[q], v[r][q]);
      }
    }
    float bvv[8], gv[8], bb[8];
#pragma unroll
    for (int q = 0; q < 8; ++q) {
      bvv[q] = bo[c * DD + q * 64 + lane];
      gv[q] = cg[c * DD + q * 64 + lane];
      bb[q] = cbv[c * DD + q * 64 + lane];
    }
#pragma unroll
    for (int r = 0; r < 4; ++r) {
      float s = 0.f, s2 = 0.f;
#pragma unroll
      for (int q = 0; q < 8; ++q) {
        float xv = v[r][q] + bvv[q];
        v[r][q] = xv; s += xv; s2 += xv * xv;
      }
      wred2(s, s2);
      float mean = s * (1.f / 512.f);
      float inv = rsqrtf(s2 * (1.f / 512.f) - mean * mean + 1e-5f);
#pragma unroll
      for (int q = 0; q < 8; ++q)
        mixed[r][q] += ((v[r][q] - mean) * inv * gv[q] + bb[q]) * 0.25f;
    }
  }
  float gg[8], gb[8];
#pragma unroll
  for (int q = 0; q < 8; ++q) { gg[q] = g1[q * 64 + lane]; gb[q] = b1v[q * 64 + lane]; }
#pragma unroll
  for (int r = 0; r < 4; ++r) {
    float xv[8]; float s = 0.f, s2 = 0.f;
#pragma unroll
    for (int q = 0; q < 8; ++q) {
      float t = h[(size_t)(row0 + r) * DD + q * 64 + lane] + mixed[r][q];
      xv[q] = t; s += t; s2 += t * t;
    }
    wred2(s, s2);
    float mean = s * (1.f / 512.f);
    float inv = rsqrtf(s2 * (1.f / 512.f) - mean * mean + 1e-5f);
#pragma unroll
    for (int q = 0; q < 8; ++q) {
      float val = (xv[q] - mean) * inv * gg[q] + gb[q];
      h1[(size_t)(row0 + r) * DD + q * 64 + lane] = val;
      h1b[(size_t)(row0 + r) * DD + q * 64 + lane] = (_Float16)val;
    }
  }
}

// out_row = LN(a_row (+ r_row)) * g + b.  One wave per row.
template <int RES, int HOUT>
__global__ __launch_bounds__(256) void ln_res(const float* __restrict__ a,
                                              const float* __restrict__ rr,
                                              const float* __restrict__ g,
                                              const float* __restrict__ b,
                                              float* __restrict__ o,
                                              _Float16* __restrict__ ob) {
  int wave = threadIdx.x >> 6, lane = threadIdx.x & 63;
  int row = blockIdx.x * 4 + wave;
  float xv[8]; float s = 0.f, s2 = 0.f;
#pragma unroll
  for (int q = 0; q < 8; ++q) {
    float t = a[(size_t)row * DD + q * 64 + lane];
    if (RES) t += rr[(size_t)row * DD + q * 64 + lane];
    xv[q] = t; s += t; s2 += t * t;
  }
  wred2(s, s2);
  float mean = s * (1.f / 512.f);
  float inv = rsqrtf(s2 * (1.f / 512.f) - mean * mean + 1e-5f);
#pragma unroll
  for (int q = 0; q < 8; ++q) {
    float val = (xv[q] - mean) * inv * g[q * 64 + lane] + b[q * 64 + lane];
    o[(size_t)row * DD + q * 64 + lane] = val;
    if (HOUT) ob[(size_t)row * DD + q * 64 + lane] = (_Float16)val;
  }
}

// ---------------------------------------------------------------------------
// Pooling + head
// ---------------------------------------------------------------------------
__global__ __launch_bounds__(256) void pool1(const float* __restrict__ h,
                                             float* __restrict__ part) {
  int b = blockIdx.y, tc = blockIdx.x;   // grid (16,8)
  for (int d = threadIdx.x; d < DD; d += 256) {
    float s = 0.f;
    for (int t = tc * 128; t < (tc + 1) * 128; ++t)
      s += h[((size_t)b * TT + t) * DD + d];
    part[(size_t)(b * 16 + tc) * DD + d] = s;
  }
}

__global__ __launch_bounds__(512) void pool2(const float* __restrict__ part,
                                             float* __restrict__ pooled) {
  int b = blockIdx.x;
  int d = threadIdx.x;
  float s = 0.f;
#pragma unroll
  for (int tc = 0; tc < 16; ++tc) s += part[(size_t)(b * 16 + tc) * DD + d];
  pooled[(size_t)b * DD + d] = s * (1.f / 2048.f);
}

__global__ __launch_bounds__(256) void head1(const float* __restrict__ pooled,
                                             const float* __restrict__ W1,
                                             const float* __restrict__ b1,
                                             float* __restrict__ hid) {
  int b = blockIdx.x, n = threadIdx.x;
  float s = b1[n];
  for (int d = 0; d < DD; ++d) s += pooled[(size_t)b * DD + d] * W1[(size_t)n * DD + d];
  hid[(size_t)b * 256 + n] = 0.5f * s * (1.f + erff(s * 0.7071067811865475f));
}

__global__ __launch_bounds__(64) void head2(const float* __restrict__ hid,
                                            const float* __restrict__ W2,
                                            const float* __restrict__ b2,
                                            float* __restrict__ out) {
  int b = blockIdx.x, lane = threadIdx.x;
  float a0 = 0.f, a1 = 0.f;
#pragma unroll
  for (int q = 0; q < 4; ++q) {
    int n = lane + q * 64;
    float hv = hid[(size_t)b * 256 + n];
    a0 = fmaf(hv, W2[n], a0);
    a1 = fmaf(hv, W2[256 + n], a1);
  }
  wred2(a0, a1);
  if (lane == 0) {
    out[b * 2 + 0] = a0 + b2[0];
    out[b * 2 + 1] = a1 + b2[1];
  }
}

// ---------------------------------------------------------------------------
// Launch
// ---------------------------------------------------------------------------
extern "C" void kernel_launch(void* const* d_in, const int* in_sizes, int n_in,
                              void* d_out, int out_size, void* d_ws, size_t ws_size,
                              hipStream_t stream) {
  const float* x    = (const float*)d_in[0];
  const float* Win  = (const float*)d_in[1];
  const float* bin_ = (const float*)d_in[2];
  const float* pos  = (const float*)d_in[3];
  const float* alpha= (const float*)d_in[4];
  const float* omega= (const float*)d_in[5];
  const float* cWin = (const float*)d_in[6];
  const float* R    = (const float*)d_in[7];
  const float* Wout = (const float*)d_in[8];
  const float* bout = (const float*)d_in[9];
  const float* clng = (const float*)d_in[10];
  const float* clnb = (const float*)d_in[11];
  const float* ln1g = (const float*)d_in[12];
  const float* ln1b = (const float*)d_in[13];
  const float* Wg   = (const float*)d_in[14];
  const float* bg   = (const float*)d_in[15];
  const float* Wu   = (const float*)d_in[16];
  const float* bu   = (const float*)d_in[17];
  const float* Wd   = (const float*)d_in[18];
  const float* bd   = (const float*)d_in[19];
  const float* ln2g = (const float*)d_in[20];
  const float* ln2b = (const float*)d_in[21];
  const float* normg= (const float*)d_in[22];
  const float* normb= (const float*)d_in[23];
  const float* W1   = (const float*)d_in[24];
  const float* b1   = (const float*)d_in[25];
  const float* W2   = (const float*)d_in[26];
  const float* b2   = (const float*)d_in[27];
  float* out = (float*)d_out;
  char* ws = (char*)d_ws;

  // workspace layout (bytes)
  float*     H    = (float*)(ws + 0);              // 32 MB fp32
  float*     H1   = (float*)(ws + 33554432);       // 32 MB fp32
  _Float16*  Pb   = (_Float16*)(ws + 67108864);    // 32 MB f16 (16384x1024)
  _Float16*  xb   = (_Float16*)(ws + 67108864);    // alias: dead before Pb used
  float*     U    = (float*)(ws + 67108864);       // alias: dead before gateup
  float*     RS   = (float*)(ws + 71303168);       // alias inside Pb region
  _Float16*  H1b  = (_Float16*)(ws + 100663296);   // 16 MB f16; doubles as Hb
  _Float16*  CWRb = (_Float16*)(ws + 117440512);   // 384 KB f16
  float*     WOT  = (float*)(ws + 118226944);      // 768 KB
  _Float16*  Winb = (_Float16*)(ws + 119013376);   // 512 KB
  _Float16*  Wgb  = (_Float16*)(ws + 119537664);   // 6 MB
  _Float16*  Wub  = (_Float16*)(ws + 125829120);   // 6 MB
  _Float16*  Wdb  = (_Float16*)(ws + 132120576);   // 6 MB
  float*     MB   = (float*)(ws + 138412032);      // 48 KB
  float*     MSB  = (float*)(ws + 138461184);      // 48 KB
  float*     E    = (float*)(ws + 138510336);      // 128 KB
  float*     CI   = (float*)(ws + 138641408);      // 128 KB
  float*     PART = (float*)(ws + 138772480);      // 256 KB
  float*     POOL = (float*)(ws + 139034624);      // 16 KB
  float*     HID  = (float*)(ws + 139050496);      // 8 KB

  // f16 weight/input conversion
  hipLaunchKernelGGL(to_half, dim3(8192), dim3(256), 0, stream, x, xb, 2097152);
  hipLaunchKernelGGL(to_half, dim3(256),  dim3(256), 0, stream, Win, Winb, 65536);
  hipLaunchKernelGGL(to_half, dim3(3072), dim3(256), 0, stream, Wg, Wgb, 786432);
  hipLaunchKernelGGL(to_half, dim3(3072), dim3(256), 0, stream, Wu, Wub, 786432);
  hipLaunchKernelGGL(to_half, dim3(3072), dim3(256), 0, stream, Wd, Wdb, 786432);

  // scan weight prep
  hipLaunchKernelGGL(fold_cwin, dim3(384), dim3(256), 0, stream, cWin, R, CWRb);
  hipLaunchKernelGGL(transpose_wout, dim3(384), dim3(256), 0, stream, Wout, WOT);
  hipLaunchKernelGGL(build_M, dim3(24), dim3(256), 0, stream, alpha, omega, R, MB);
  hipLaunchKernelGGL(matpow, dim3(24), dim3(256), 0, stream, MB, MSB);

  // input projection + pos emb (f16 MFMA); also writes Hb (=H1b slot)
  hipLaunchKernelGGL((mgemm<2, 1>), dim3(4, 128), dim3(256), 0, stream,
                     xb, Winb, bin_, pos, H, H1b, MM_ROWS, DD, DD);

  for (int l = 0; l < LL; ++l) {
    hipLaunchKernelGGL(cwin16, dim3(1, 128), dim3(256), 0, stream,
                       H1b, CWRb + (size_t)l * 64 * DD, U);
    hipLaunchKernelGGL(scanA, dim3(256), dim3(64), 0, stream, U, MB + l * 2048, E);
    hipLaunchKernelGGL(scanB, dim3(1), dim3(512), 0, stream, E, MSB + l * 2048, CI);
    hipLaunchKernelGGL(scanC, dim3(256), dim3(64), 0, stream, U, MB + l * 2048, CI, RS);
    hipLaunchKernelGGL(mix_ln, dim3(1024), dim3(256), 0, stream,
                       RS, WOT + (size_t)l * 32768, bout + l * 2048,
                       clng + l * 2048, clnb + l * 2048, H,
                       ln1g + l * 512, ln1b + l * 512, H1, H1b);
    hipLaunchKernelGGL(mgemm_gateup, dim3(16, 128), dim3(256), 0, stream,
                       H1b, Wgb + (size_t)l * 524288, Wub + (size_t)l * 524288,
                       bg + l * 1024, bu + l * 1024, Pb);
    hipLaunchKernelGGL((mgemm<1, 0>), dim3(4, 128), dim3(256), 0, stream,
                       Pb, Wdb + (size_t)l * 524288, bd + l * 512,
                       (const float*)nullptr, H, (_Float16*)nullptr,
                       MM_ROWS, DD, 1024);
    hipLaunchKernelGGL((ln_res<1, 1>), dim3(4096), dim3(256), 0, stream,
                       H1, H, ln2g + l * 512, ln2b + l * 512, H, H1b);
  }

  hipLaunchKernelGGL((ln_res<0, 0>), dim3(4096), dim3(256), 0, stream,
                     H, (const float*)nullptr, normg, normb, H, (_Float16*)nullptr);
  hipLaunchKernelGGL(pool1, dim3(16, 8), dim3(256), 0, stream, H, PART);
  hipLaunchKernelGGL(pool2, dim3(8), dim3(512), 0, stream, PART, POOL);
  hipLaunchKernelGGL(head1, dim3(8), dim3(256), 0, stream, POOL, W1, b1, HID);
  hipLaunchKernelGGL(head2, dim3(8), dim3(64), 0, stream, HID, W2, b2, out);
}

// Round 5
// 1980.290 us; speedup vs baseline: 2.6708x; 1.0612x over previous
//
#include <hip/hip_runtime.h>

// ---------------------------------------------------------------------------
// TEN_Encoder: B=8 T=2048 D=512 C=4 K=16 L=6.
// Big GEMMs: f16 MFMA, 256x128 tile, 8 waves, 3-buf depth-2 prefetch,
// counted vmcnt + raw s_barrier.  Gate/up fused via 16-row-interleaved Wgu.
// Scan path (SCHUNK=32) + mix_ln + LNs in fp32.
// ---------------------------------------------------------------------------

#define BB 8
#define TT 2048
#define DD 512
#define LL 6
#define MM_ROWS 16384
#define SCHUNK 32
#define NCHUNK 64

typedef __attribute__((ext_vector_type(4))) float f32x4;
typedef __attribute__((ext_vector_type(8))) _Float16 f16x8;
typedef __attribute__((ext_vector_type(4))) _Float16 f16x4;

#define GLOAD16(g, l)                                                          \
  __builtin_amdgcn_global_load_lds(                                            \
      (const __attribute__((address_space(1))) void*)(g),                      \
      (__attribute__((address_space(3))) void*)(l), 16, 0, 0)

#define VM3 asm volatile("s_waitcnt vmcnt(3)" ::: "memory")
#define VM0 asm volatile("s_waitcnt vmcnt(0)" ::: "memory")
#define BARRIER() __builtin_amdgcn_s_barrier()

__device__ inline void wred2(float& a, float& b) {
#pragma unroll
  for (int off = 32; off; off >>= 1) {
    a += __shfl_xor(a, off);
    b += __shfl_xor(b, off);
  }
}

// ---------------------------------------------------------------------------
// fp32 -> f16 convert (RNE), 4 elems/thread
// ---------------------------------------------------------------------------
__global__ __launch_bounds__(256) void to_half(const float* __restrict__ s,
                                               _Float16* __restrict__ d, int n4) {
  int i = blockIdx.x * 256 + threadIdx.x;
  if (i < n4) {
    f32x4 v = *((const f32x4*)s + i);
    f16x4 o;
#pragma unroll
    for (int q = 0; q < 4; ++q) o[q] = (_Float16)v[q];
    *((f16x4*)d + i) = o;
  }
}

// Interleaved gate/up weight: Wgu[l][r][d], r=32*(n>>4)+16*isup+(n&15).
// 6*2048 rows x 512 cols.  grid 6144 x 256 thr, 4 cols/thread.
__global__ __launch_bounds__(256) void wgu_prep(const float* __restrict__ Wg,
                                                const float* __restrict__ Wu,
                                                _Float16* __restrict__ Wgu) {
  int idx = blockIdx.x * 256 + threadIdx.x;
  int row = idx >> 7;                 // 0..12287
  int col = (idx & 127) << 2;
  int l = row >> 11, r = row & 2047;
  int n = ((r >> 5) << 4) | (r & 15);
  int isup = (r >> 4) & 1;
  const float* src = (isup ? Wu : Wg) + (size_t)l * 524288 + (size_t)n * 512 + col;
  f32x4 v = *(const f32x4*)src;
  f16x4 o;
#pragma unroll
  for (int q = 0; q < 4; ++q) o[q] = (_Float16)v[q];
  *(f16x4*)(Wgu + (size_t)row * 512 + col) = o;
}

// ---------------------------------------------------------------------------
// Weight prep (scan path)
// ---------------------------------------------------------------------------
__global__ __launch_bounds__(256) void fold_cwin(const float* __restrict__ cWin,
                                                 const float* __restrict__ R,
                                                 _Float16* __restrict__ cWinR) {
  int bid = blockIdx.x;            // (l*4+c)*16 + j, 384 blocks
  int j = bid & 15, lc = bid >> 4;
  int l = lc >> 2;
  for (int d = threadIdx.x; d < DD; d += 256) {
    float s = 0.f;
#pragma unroll
    for (int k = 0; k < 16; ++k)
      s += cWin[(lc * 16 + k) * DD + d] * R[(lc * 16 + k) * 16 + j];
    cWinR[((size_t)l * 64 + (lc & 3) * 16 + j) * DD + d] = (_Float16)s;
  }
}

__global__ __launch_bounds__(256) void transpose_wout(const float* __restrict__ Wout,
                                                      float* __restrict__ WoutT) {
  int bid = blockIdx.x;            // lc*16 + k, 384 blocks
  int k = bid & 15, lc = bid >> 4;
  for (int d = threadIdx.x; d < DD; d += 256)
    WoutT[(size_t)bid * DD + d] = Wout[((size_t)lc * DD + d) * 16 + k];
}

__global__ __launch_bounds__(256) void build_M(const float* __restrict__ alpha,
                                               const float* __restrict__ omega,
                                               const float* __restrict__ R,
                                               float* __restrict__ Mall) {
  int lc = blockIdx.x;             // 24 blocks
  int tid = threadIdx.x;           // k*16+j
  int k = tid >> 4;
  float a = alpha[lc * 16 + k];
  float mag = 1.f / (1.f + expf(-a));
  float om = omega[lc * 16 + k];
  float rr = R[(lc * 16 + k) * 16 + (tid & 15)];
  Mall[lc * 512 + tid] = mag * cosf(om) * rr;
  Mall[lc * 512 + 256 + tid] = mag * sinf(om) * rr;
}

// MS = M^SCHUNK via 5 complex squarings (SCHUNK = 32 = 2^5)
__global__ __launch_bounds__(256) void matpow(const float* __restrict__ M,
                                              float* __restrict__ MS) {
  __shared__ float cr[256], ci[256];
  int lc = blockIdx.x, tid = threadIdx.x;
  cr[tid] = M[lc * 512 + tid];
  ci[tid] = M[lc * 512 + 256 + tid];
  __syncthreads();
  int k = tid >> 4, j = tid & 15;
  for (int it = 0; it < 5; ++it) {
    float sr = 0.f, si = 0.f;
#pragma unroll
    for (int m = 0; m < 16; ++m) {
      float ar = cr[k * 16 + m], ai = ci[k * 16 + m];
      float br = cr[m * 16 + j], bi = ci[m * 16 + j];
      sr += ar * br - ai * bi;
      si += ar * bi + ai * br;
    }
    __syncthreads();
    cr[tid] = sr; ci[tid] = si;
    __syncthreads();
  }
  MS[lc * 512 + tid] = cr[tid];
  MS[lc * 512 + 256 + tid] = ci[tid];
}

// ---------------------------------------------------------------------------
// 256x128 f16 MFMA GEMM: out(fp32) = A(MxK) * W(NxK)^T + epilogue.
// 8 waves x (64x64), BK=32, 3-buf depth-2, counted vmcnt.
// A stage: 2 loads/thr; B stage: 1 load/thr  -> VM3.
// EPI: 1 = +bias ; 2 = +bias +pos[row%T].  HOUT: also write f16 to ob.
// ---------------------------------------------------------------------------
template <int EPI, int HOUT>
__global__ __launch_bounds__(512, 4) void mgemm256(const _Float16* __restrict__ A,
                                                   const _Float16* __restrict__ W,
                                                   const float* __restrict__ bias,
                                                   const float* __restrict__ pos,
                                                   float* __restrict__ out,
                                                   _Float16* __restrict__ ob,
                                                   int M, int N, int K) {
  __shared__ alignas(16) _Float16 As[3][4][256][8];   // 48 KB
  __shared__ alignas(16) _Float16 Bs[3][4][128][8];   // 24 KB
  const int tid = threadIdx.x;
  const int wv = tid >> 6, lane = tid & 63;
  const int m0 = blockIdx.y << 8, n0 = blockIdx.x << 7;
  const int wr = (wv >> 1) << 6, wc = (wv & 1) << 6;
  const int r16 = lane & 15, half = lane >> 4;
  const _Float16* Ap = A + (size_t)(m0 + (tid & 255)) * K + ((tid >> 8) << 3);
  const _Float16* Wp = W + (size_t)(n0 + (tid & 127)) * K + ((tid >> 7) << 3);
  const int lb = wv << 10;
  f32x4 acc[4][4] = {};

#define MSTG(buf, kk)                                                          \
  {                                                                            \
    GLOAD16(Ap + (kk), (char*)As[buf] + lb);                                   \
    GLOAD16(Ap + (kk) + 16, (char*)As[buf] + lb + 8192);                       \
    GLOAD16(Wp + (kk), (char*)Bs[buf] + lb);                                   \
  }

  const int nt = K >> 5;
  MSTG(0, 0);
  MSTG(1, 32);
  int cur = 0, nxt = 2;
  for (int t = 0; t < nt; ++t) {
    if (t + 1 < nt) { VM3; } else { VM0; }
    BARRIER();
    if (t + 2 < nt) MSTG(nxt, (t + 2) << 5);
    f16x8 af[4], bf[4];
#pragma unroll
    for (int i = 0; i < 4; ++i)
      af[i] = *(const f16x8*)&As[cur][half][wr + (i << 4) + r16][0];
#pragma unroll
    for (int j = 0; j < 4; ++j)
      bf[j] = *(const f16x8*)&Bs[cur][half][wc + (j << 4) + r16][0];
#pragma unroll
    for (int i = 0; i < 4; ++i)
#pragma unroll
      for (int j = 0; j < 4; ++j)
        acc[i][j] = __builtin_amdgcn_mfma_f32_16x16x32_f16(af[i], bf[j], acc[i][j], 0, 0, 0);
    cur = (cur == 2) ? 0 : cur + 1;
    nxt = (nxt == 2) ? 0 : nxt + 1;
  }
#undef MSTG
#pragma unroll
  for (int i = 0; i < 4; ++i)
#pragma unroll
    for (int j = 0; j < 4; ++j) {
      int n = n0 + wc + (j << 4) + r16;
      float bv = bias ? bias[n] : 0.f;
#pragma unroll
      for (int r = 0; r < 4; ++r) {
        int m = m0 + wr + (i << 4) + (half << 2) + r;
        float v = acc[i][j][r] + bv;
        if (EPI == 2) v += pos[(size_t)(m & (TT - 1)) * DD + n];
        out[(size_t)m * N + n] = v;
        if (HOUT) ob[(size_t)m * N + n] = (_Float16)v;
      }
    }
}

// Fused gate/up on interleaved Wgu (2048x512): 256x128 tile, 8 waves.
// acc[i][2jp] = gate, acc[i][2jp+1] = up for the SAME n.  M=16384, K=512.
__global__ __launch_bounds__(512, 4) void gateup256(const _Float16* __restrict__ A,
                                                    const _Float16* __restrict__ Wgu,
                                                    const float* __restrict__ bg,
                                                    const float* __restrict__ bu,
                                                    _Float16* __restrict__ P) {
  __shared__ alignas(16) _Float16 As[3][4][256][8];
  __shared__ alignas(16) _Float16 Bs[3][4][128][8];
  const int tid = threadIdx.x;
  const int wv = tid >> 6, lane = tid & 63;
  const int m0 = blockIdx.y << 8, n0 = blockIdx.x << 7;
  const int wr = (wv >> 1) << 6, wc = (wv & 1) << 6;
  const int r16 = lane & 15, half = lane >> 4;
  const _Float16* Ap = A + (size_t)(m0 + (tid & 255)) * 512 + ((tid >> 8) << 3);
  const _Float16* Wp = Wgu + (size_t)(n0 + (tid & 127)) * 512 + ((tid >> 7) << 3);
  const int lb = wv << 10;
  f32x4 acc[4][4] = {};

#define GSTG(buf, kk)                                                          \
  {                                                                            \
    GLOAD16(Ap + (kk), (char*)As[buf] + lb);                                   \
    GLOAD16(Ap + (kk) + 16, (char*)As[buf] + lb + 8192);                       \
    GLOAD16(Wp + (kk), (char*)Bs[buf] + lb);                                   \
  }

  GSTG(0, 0);
  GSTG(1, 32);
  int cur = 0, nxt = 2;
  for (int t = 0; t < 16; ++t) {
    if (t + 1 < 16) { VM3; } else { VM0; }
    BARRIER();
    if (t + 2 < 16) GSTG(nxt, (t + 2) << 5);
    f16x8 af[4], bf[4];
#pragma unroll
    for (int i = 0; i < 4; ++i)
      af[i] = *(const f16x8*)&As[cur][half][wr + (i << 4) + r16][0];
#pragma unroll
    for (int j = 0; j < 4; ++j)
      bf[j] = *(const f16x8*)&Bs[cur][half][wc + (j << 4) + r16][0];
#pragma unroll
    for (int i = 0; i < 4; ++i)
#pragma unroll
      for (int j = 0; j < 4; ++j)
        acc[i][j] = __builtin_amdgcn_mfma_f32_16x16x32_f16(af[i], bf[j], acc[i][j], 0, 0, 0);
    cur = (cur == 2) ? 0 : cur + 1;
    nxt = (nxt == 2) ? 0 : nxt + 1;
  }
#undef GSTG
#pragma unroll
  for (int i = 0; i < 4; ++i)
#pragma unroll
    for (int jp = 0; jp < 2; ++jp) {
      int n = (blockIdx.x << 6) + (wc >> 1) + (jp << 4) + r16;
      float bgv = bg[n], buv = bu[n];
#pragma unroll
      for (int r = 0; r < 4; ++r) {
        int m = m0 + wr + (i << 4) + (half << 2) + r;
        float g = acc[i][2 * jp][r] + bgv;
        float u = acc[i][2 * jp + 1][r] + buv;
        float sg = g / (1.f + expf(-g));
        P[(size_t)m * 1024 + n] = (_Float16)(sg * u);
      }
    }
}

// cWin projection f16 MFMA: u = Hb(16384x512) * cWinR(64x512)^T, scatter to
// scan layout u[t][cb][j].  128x64 tile, 4 waves x (64x32).
__global__ __launch_bounds__(256) void cwin16(const _Float16* __restrict__ A,
                                              const _Float16* __restrict__ W,
                                              float* __restrict__ u) {
  __shared__ alignas(16) _Float16 As[3][4][128][8];
  __shared__ alignas(16) _Float16 Ws[3][4][64][8];
  const int tid = threadIdx.x;
  const int wv = tid >> 6, lane = tid & 63;
  const int m0 = blockIdx.y << 7;
  const int wr = (wv >> 1) << 6, wc = (wv & 1) << 5;
  const int r16 = lane & 15, half = lane >> 4;
  const _Float16* Ap = A + (size_t)(m0 + (tid & 127)) * 512 + ((tid >> 7) << 3);
  const _Float16* Wp = W + (size_t)(tid & 63) * 512 + ((tid >> 6) << 3);
  const int lb = wv << 10;
  f32x4 acc[4][2] = {};

#define CSTG(buf, kk)                                                          \
  {                                                                            \
    GLOAD16(Ap + (kk), (char*)As[buf] + lb);                                   \
    GLOAD16(Ap + (kk) + 16, (char*)As[buf] + lb + 4096);                       \
    GLOAD16(Wp + (kk), (char*)Ws[buf] + lb);                                   \
  }

  CSTG(0, 0);
  CSTG(1, 32);
  int cur = 0, nxt = 2;
  for (int t = 0; t < 16; ++t) {
    if (t + 1 < 16) { VM3; } else { VM0; }
    BARRIER();
    if (t + 2 < 16) CSTG(nxt, (t + 2) << 5);
    f16x8 af[4], wf[2];
#pragma unroll
    for (int i = 0; i < 4; ++i)
      af[i] = *(const f16x8*)&As[cur][half][wr + (i << 4) + r16][0];
#pragma unroll
    for (int j = 0; j < 2; ++j)
      wf[j] = *(const f16x8*)&Ws[cur][half][wc + (j << 4) + r16][0];
#pragma unroll
    for (int i = 0; i < 4; ++i)
#pragma unroll
      for (int j = 0; j < 2; ++j)
        acc[i][j] = __builtin_amdgcn_mfma_f32_16x16x32_f16(af[i], wf[j], acc[i][j], 0, 0, 0);
    cur = (cur == 2) ? 0 : cur + 1;
    nxt = (nxt == 2) ? 0 : nxt + 1;
  }
#undef CSTG
#pragma unroll
  for (int i = 0; i < 4; ++i)
#pragma unroll
    for (int j = 0; j < 2; ++j) {
      int n = wc + (j << 4) + r16;
      int c = n >> 4, jj = n & 15;
#pragma unroll
      for (int r = 0; r < 4; ++r) {
        int m = m0 + wr + (i << 4) + (half << 2) + r;
        int t = m & (TT - 1), b = m >> 11;
        u[((size_t)t * 32 + c * 8 + b) * 16 + jj] = acc[i][j][r];
      }
    }
}

// ---------------------------------------------------------------------------
// Chunked linear scan (fp32).  SCHUNK=32, NCHUNK=64, 2048 units.
// ---------------------------------------------------------------------------
#define SCAN_STEP(uv)                                                          \
  {                                                                            \
    float nr0 = (uv), nr1 = 0.f, ni0 = 0.f, ni1 = 0.f;                         \
    _Pragma("unroll") for (int k = 0; k < 16; k += 2) {                        \
      float rka = __shfl(zr, sb | k), ika = __shfl(zi, sb | k);                \
      float rkb = __shfl(zr, sb | (k + 1)), ikb = __shfl(zi, sb | (k + 1));    \
      nr0 = fmaf(rka, Mr[k], nr0);  nr0 = fmaf(-ika, Mi[k], nr0);              \
      ni0 = fmaf(rka, Mi[k], ni0);  ni0 = fmaf(ika, Mr[k], ni0);               \
      nr1 = fmaf(rkb, Mr[k + 1], nr1); nr1 = fmaf(-ikb, Mi[k + 1], nr1);       \
      ni1 = fmaf(rkb, Mi[k + 1], ni1); ni1 = fmaf(ikb, Mr[k + 1], ni1);        \
    }                                                                          \
    zr = nr0 + nr1; zi = ni0 + ni1;                                            \
  }

__global__ __launch_bounds__(64) void scanA(const float* __restrict__ u,
                                            const float* __restrict__ M,
                                            float* __restrict__ E) {
  int unit = blockIdx.x * 4 + (threadIdx.x >> 4);   // 2048 units
  int j = threadIdx.x & 15;
  int sb = threadIdx.x & 48;
  int g = unit >> 5, cb = unit & 31, c = cb >> 3;
  float Mr[16], Mi[16];
  const float* Mc = M + c * 512;
#pragma unroll
  for (int k = 0; k < 16; ++k) { Mr[k] = Mc[k * 16 + j]; Mi[k] = Mc[256 + k * 16 + j]; }
  float zr = 0.f, zi = 0.f;
  const float* up = u + ((size_t)g * SCHUNK * 32 + cb) * 16 + j;
  for (int s = 0; s < SCHUNK; ++s) {
    float uv = up[(size_t)s * 512];
    SCAN_STEP(uv);
  }
  float* Ep = E + ((size_t)unit * 16 + j) * 2;
  Ep[0] = zr; Ep[1] = zi;
}

__global__ __launch_bounds__(512) void scanB(const float* __restrict__ E,
                                             const float* __restrict__ MS,
                                             float* __restrict__ CI) {
  int cb = threadIdx.x >> 4, j = threadIdx.x & 15, sb = threadIdx.x & 48;
  int c = cb >> 3;
  float Mr[16], Mi[16];
  const float* Mc = MS + c * 512;
#pragma unroll
  for (int k = 0; k < 16; ++k) { Mr[k] = Mc[k * 16 + j]; Mi[k] = Mc[256 + k * 16 + j]; }
  float zr = 0.f, zi = 0.f;
  for (int g = 0; g < NCHUNK; ++g) {
    float* cp = CI + (((size_t)g * 32 + cb) * 16 + j) * 2;
    cp[0] = zr; cp[1] = zi;
    const float* ep = E + (((size_t)g * 32 + cb) * 16 + j) * 2;
    float er = ep[0], ei = ep[1];
    SCAN_STEP(er);
    zi += ei;
  }
}

__global__ __launch_bounds__(64) void scanC(const float* __restrict__ u,
                                            const float* __restrict__ M,
                                            const float* __restrict__ CI,
                                            float* __restrict__ rs) {
  int unit = blockIdx.x * 4 + (threadIdx.x >> 4);
  int j = threadIdx.x & 15;
  int sb = threadIdx.x & 48;
  int g = unit >> 5, cb = unit & 31, c = cb >> 3, b = cb & 7;
  float Mr[16], Mi[16];
  const float* Mc = M + c * 512;
#pragma unroll
  for (int k = 0; k < 16; ++k) { Mr[k] = Mc[k * 16 + j]; Mi[k] = Mc[256 + k * 16 + j]; }
  const float* cp = CI + ((size_t)unit * 16 + j) * 2;
  float zr = cp[0], zi = cp[1];
  int t0 = g * SCHUNK;
  const float* up = u + ((size_t)t0 * 32 + cb) * 16 + j;
  float* rp = rs + (((size_t)b * TT + t0) * 4 + c) * 16 + j;
  for (int s = 0; s < SCHUNK; ++s) {
    float uv = up[(size_t)s * 512];
    SCAN_STEP(uv);
    rp[(size_t)s * 64] = zr;
  }
}

// ---------------------------------------------------------------------------
// Fused: cell_out proj + per-cell LN + mean + residual + LN1.
// ---------------------------------------------------------------------------
__global__ __launch_bounds__(256) void mix_ln(const float* __restrict__ rs,
                                              const float* __restrict__ WoutT,
                                              const float* __restrict__ bo,
                                              const float* __restrict__ cg,
                                              const float* __restrict__ cbv,
                                              const float* __restrict__ h,
                                              const float* __restrict__ g1,
                                              const float* __restrict__ b1v,
                                              float* __restrict__ h1,
                                              _Float16* __restrict__ h1b) {
  int wave = threadIdx.x >> 6, lane = threadIdx.x & 63;
  int row0 = blockIdx.x * 16 + wave * 4;
  float rsv[4];
#pragma unroll
  for (int r = 0; r < 4; ++r) rsv[r] = rs[(size_t)(row0 + r) * 64 + lane];
  float mixed[4][8];
#pragma unroll
  for (int r = 0; r < 4; ++r)
#pragma unroll
    for (int q = 0; q < 8; ++q) mixed[r][q] = 0.f;
  for (int c = 0; c < 4; ++c) {
    float v[4][8];
#pragma unroll
    for (int r = 0; r < 4; ++r)
#pragma unroll
      for (int q = 0; q < 8; ++q) v[r][q] = 0.f;
#pragma unroll
    for (int k = 0; k < 16; ++k) {
      float w[8];
#pragma unroll
      for (int q = 0; q < 8; ++q) w[q] = WoutT[(size_t)(c * 16 + k) * DD + q * 64 + lane];
#pragma unroll
      for (int r = 0; r < 4; ++r) {
        float rv = __shfl(rsv[r], c * 16 + k);
#pragma unroll
        for (int q = 0; q < 8; ++q) v[r][q] = fmaf(rv, w[q], v[r][q]);
      }
    }
    float bvv[8], gv[8], bb[8];
#pragma unroll
    for (int q = 0; q < 8; ++q) {
      bvv[q] = bo[c * DD + q * 64 + lane];
      gv[q] = cg[c * DD + q * 64 + lane];
      bb[q] = cbv[c * DD + q * 64 + lane];
    }
#pragma unroll
    for (int r = 0; r < 4; ++r) {
      float s = 0.f, s2 = 0.f;
#pragma unroll
      for (int q = 0; q < 8; ++q) {
        float xv = v[r][q] + bvv[q];
        v[r][q] = xv; s += xv; s2 += xv * xv;
      }
      wred2(s, s2);
      float mean = s * (1.f / 512.f);
      float inv = rsqrtf(s2 * (1.f / 512.f) - mean * mean + 1e-5f);
#pragma unroll
      for (int q = 0; q < 8; ++q)
        mixed[r][q] += ((v[r][q] - mean) * inv * gv[q] + bb[q]) * 0.25f;
    }
  }
  float gg[8], gb[8];
#pragma unroll
  for (int q = 0; q < 8; ++q) { gg[q] = g1[q * 64 + lane]; gb[q] = b1v[q * 64 + lane]; }
#pragma unroll
  for (int r = 0; r < 4; ++r) {
    float xv[8]; float s = 0.f, s2 = 0.f;
#pragma unroll
    for (int q = 0; q < 8; ++q) {
      float t = h[(size_t)(row0 + r) * DD + q * 64 + lane] + mixed[r][q];
      xv[q] = t; s += t; s2 += t * t;
    }
    wred2(s, s2);
    float mean = s * (1.f / 512.f);
    float inv = rsqrtf(s2 * (1.f / 512.f) - mean * mean + 1e-5f);
#pragma unroll
    for (int q = 0; q < 8; ++q) {
      float val = (xv[q] - mean) * inv * gg[q] + gb[q];
      h1[(size_t)(row0 + r) * DD + q * 64 + lane] = val;
      h1b[(size_t)(row0 + r) * DD + q * 64 + lane] = (_Float16)val;
    }
  }
}

// out_row = LN(a_row (+ r_row)) * g + b.  One wave per row.
template <int RES, int HOUT>
__global__ __launch_bounds__(256) void ln_res(const float* __restrict__ a,
                                              const float* __restrict__ rr,
                                              const float* __restrict__ g,
                                              const float* __restrict__ b,
                                              float* __restrict__ o,
                                              _Float16* __restrict__ ob) {
  int wave = threadIdx.x >> 6, lane = threadIdx.x & 63;
  int row = blockIdx.x * 4 + wave;
  float xv[8]; float s = 0.f, s2 = 0.f;
#pragma unroll
  for (int q = 0; q < 8; ++q) {
    float t = a[(size_t)row * DD + q * 64 + lane];
    if (RES) t += rr[(size_t)row * DD + q * 64 + lane];
    xv[q] = t; s += t; s2 += t * t;
  }
  wred2(s, s2);
  float mean = s * (1.f / 512.f);
  float inv = rsqrtf(s2 * (1.f / 512.f) - mean * mean + 1e-5f);
#pragma unroll
  for (int q = 0; q < 8; ++q) {
    float val = (xv[q] - mean) * inv * g[q * 64 + lane] + b[q * 64 + lane];
    o[(size_t)row * DD + q * 64 + lane] = val;
    if (HOUT) ob[(size_t)row * DD + q * 64 + lane] = (_Float16)val;
  }
}

// ---------------------------------------------------------------------------
// Pooling + head
// ---------------------------------------------------------------------------
__global__ __launch_bounds__(256) void pool1(const float* __restrict__ h,
                                             float* __restrict__ part) {
  int b = blockIdx.y, tc = blockIdx.x;   // grid (16,8)
  for (int d = threadIdx.x; d < DD; d += 256) {
    float s = 0.f;
    for (int t = tc * 128; t < (tc + 1) * 128; ++t)
      s += h[((size_t)b * TT + t) * DD + d];
    part[(size_t)(b * 16 + tc) * DD + d] = s;
  }
}

__global__ __launch_bounds__(512) void pool2(const float* __restrict__ part,
                                             float* __restrict__ pooled) {
  int b = blockIdx.x;
  int d = threadIdx.x;
  float s = 0.f;
#pragma unroll
  for (int tc = 0; tc < 16; ++tc) s += part[(size_t)(b * 16 + tc) * DD + d];
  pooled[(size_t)b * DD + d] = s * (1.f / 2048.f);
}

__global__ __launch_bounds__(256) void head1(const float* __restrict__ pooled,
                                             const float* __restrict__ W1,
                                             const float* __restrict__ b1,
                                             float* __restrict__ hid) {
  int b = blockIdx.x, n = threadIdx.x;
  float s = b1[n];
  for (int d = 0; d < DD; ++d) s += pooled[(size_t)b * DD + d] * W1[(size_t)n * DD + d];
  hid[(size_t)b * 256 + n] = 0.5f * s * (1.f + erff(s * 0.7071067811865475f));
}

__global__ __launch_bounds__(64) void head2(const float* __restrict__ hid,
                                            const float* __restrict__ W2,
                                            const float* __restrict__ b2,
                                            float* __restrict__ out) {
  int b = blockIdx.x, lane = threadIdx.x;
  float a0 = 0.f, a1 = 0.f;
#pragma unroll
  for (int q = 0; q < 4; ++q) {
    int n = lane + q * 64;
    float hv = hid[(size_t)b * 256 + n];
    a0 = fmaf(hv, W2[n], a0);
    a1 = fmaf(hv, W2[256 + n], a1);
  }
  wred2(a0, a1);
  if (lane == 0) {
    out[b * 2 + 0] = a0 + b2[0];
    out[b * 2 + 1] = a1 + b2[1];
  }
}

// ---------------------------------------------------------------------------
// Launch
// ---------------------------------------------------------------------------
extern "C" void kernel_launch(void* const* d_in, const int* in_sizes, int n_in,
                              void* d_out, int out_size, void* d_ws, size_t ws_size,
                              hipStream_t stream) {
  const float* x    = (const float*)d_in[0];
  const float* Win  = (const float*)d_in[1];
  const float* bin_ = (const float*)d_in[2];
  const float* pos  = (const float*)d_in[3];
  const float* alpha= (const float*)d_in[4];
  const float* omega= (const float*)d_in[5];
  const float* cWin = (const float*)d_in[6];
  const float* R    = (const float*)d_in[7];
  const float* Wout = (const float*)d_in[8];
  const float* bout = (const float*)d_in[9];
  const float* clng = (const float*)d_in[10];
  const float* clnb = (const float*)d_in[11];
  const float* ln1g = (const float*)d_in[12];
  const float* ln1b = (const float*)d_in[13];
  const float* Wg   = (const float*)d_in[14];
  const float* bg   = (const float*)d_in[15];
  const float* Wu   = (const float*)d_in[16];
  const float* bu   = (const float*)d_in[17];
  const float* Wd   = (const float*)d_in[18];
  const float* bd   = (const float*)d_in[19];
  const float* ln2g = (const float*)d_in[20];
  const float* ln2b = (const float*)d_in[21];
  const float* normg= (const float*)d_in[22];
  const float* normb= (const float*)d_in[23];
  const float* W1   = (const float*)d_in[24];
  const float* b1   = (const float*)d_in[25];
  const float* W2   = (const float*)d_in[26];
  const float* b2   = (const float*)d_in[27];
  float* out = (float*)d_out;
  char* ws = (char*)d_ws;

  // workspace layout (bytes)
  float*     H    = (float*)(ws + 0);              // 32 MB fp32
  float*     H1   = (float*)(ws + 33554432);       // 32 MB fp32
  _Float16*  Pb   = (_Float16*)(ws + 67108864);    // 32 MB f16 (16384x1024)
  _Float16*  xb   = (_Float16*)(ws + 67108864);    // alias: dead before Pb used
  float*     U    = (float*)(ws + 67108864);       // alias: dead before gateup
  float*     RS   = (float*)(ws + 71303168);       // alias inside Pb region
  _Float16*  H1b  = (_Float16*)(ws + 100663296);   // 16 MB f16; doubles as Hb
  _Float16*  CWRb = (_Float16*)(ws + 117440512);   // 384 KB f16
  float*     WOT  = (float*)(ws + 118226944);      // 768 KB
  _Float16*  Winb = (_Float16*)(ws + 119013376);   // 512 KB
  _Float16*  Wgub = (_Float16*)(ws + 119537664);   // 12 MB f16 (6x2048x512)
  _Float16*  Wdb  = (_Float16*)(ws + 132120576);   // 6 MB
  float*     MB   = (float*)(ws + 138412032);      // 48 KB
  float*     MSB  = (float*)(ws + 138461184);      // 48 KB
  float*     E    = (float*)(ws + 138510336);      // 256 KB (2048 units x 16 x 2)
  float*     CI   = (float*)(ws + 138772480);      // 256 KB
  float*     PART = (float*)(ws + 139034624);      // 256 KB
  float*     POOL = (float*)(ws + 139296768);      // 16 KB
  float*     HID  = (float*)(ws + 139313152);      // 8 KB

  // f16 weight/input conversion
  hipLaunchKernelGGL(to_half, dim3(8192), dim3(256), 0, stream, x, xb, 2097152);
  hipLaunchKernelGGL(to_half, dim3(256),  dim3(256), 0, stream, Win, Winb, 65536);
  hipLaunchKernelGGL(to_half, dim3(3072), dim3(256), 0, stream, Wd, Wdb, 786432);
  hipLaunchKernelGGL(wgu_prep, dim3(6144), dim3(256), 0, stream, Wg, Wu, Wgub);

  // scan weight prep
  hipLaunchKernelGGL(fold_cwin, dim3(384), dim3(256), 0, stream, cWin, R, CWRb);
  hipLaunchKernelGGL(transpose_wout, dim3(384), dim3(256), 0, stream, Wout, WOT);
  hipLaunchKernelGGL(build_M, dim3(24), dim3(256), 0, stream, alpha, omega, R, MB);
  hipLaunchKernelGGL(matpow, dim3(24), dim3(256), 0, stream, MB, MSB);

  // input projection + pos emb; also writes Hb (=H1b slot) f16
  hipLaunchKernelGGL((mgemm256<2, 1>), dim3(4, 64), dim3(512), 0, stream,
                     xb, Winb, bin_, pos, H, H1b, MM_ROWS, DD, DD);

  for (int l = 0; l < LL; ++l) {
    hipLaunchKernelGGL(cwin16, dim3(1, 128), dim3(256), 0, stream,
                       H1b, CWRb + (size_t)l * 64 * DD, U);
    hipLaunchKernelGGL(scanA, dim3(512), dim3(64), 0, stream, U, MB + l * 2048, E);
    hipLaunchKernelGGL(scanB, dim3(1), dim3(512), 0, stream, E, MSB + l * 2048, CI);
    hipLaunchKernelGGL(scanC, dim3(512), dim3(64), 0, stream, U, MB + l * 2048, CI, RS);
    hipLaunchKernelGGL(mix_ln, dim3(1024), dim3(256), 0, stream,
                       RS, WOT + (size_t)l * 32768, bout + l * 2048,
                       clng + l * 2048, clnb + l * 2048, H,
                       ln1g + l * 512, ln1b + l * 512, H1, H1b);
    hipLaunchKernelGGL(gateup256, dim3(16, 64), dim3(512), 0, stream,
                       H1b, Wgub + (size_t)l * 1048576,
                       bg + l * 1024, bu + l * 1024, Pb);
    hipLaunchKernelGGL((mgemm256<1, 0>), dim3(4, 64), dim3(512), 0, stream,
                       Pb, Wdb + (size_t)l * 524288, bd + l * 512,
                       (const float*)nullptr, H, (_Float16*)nullptr,
                       MM_ROWS, DD, 1024);
    hipLaunchKernelGGL((ln_res<1, 1>), dim3(4096), dim3(256), 0, stream,
                       H1, H, ln2g + l * 512, ln2b + l * 512, H, H1b);
  }

  hipLaunchKernelGGL((ln_res<0, 0>), dim3(4096), dim3(256), 0, stream,
                     H, (const float*)nullptr, normg, normb, H, (_Float16*)nullptr);
  hipLaunchKernelGGL(pool1, dim3(16, 8), dim3(256), 0, stream, H, PART);
  hipLaunchKernelGGL(pool2, dim3(8), dim3(512), 0, stream, PART, POOL);
  hipLaunchKernelGGL(head1, dim3(8), dim3(256), 0, stream, POOL, W1, b1, HID);
  hipLaunchKernelGGL(head2, dim3(8), dim3(64), 0, stream, HID, W2, b2, out);
}